// Round 1
// baseline (3601.288 us; speedup 1.0000x reference)
//
#include <hip/hip_runtime.h>
#include <math.h>

#define B_   2
#define T_   2048
#define HID_ 2048
#define NH_  32
#define KH_  8
#define HD_  64
#define G_   4

// ---------------- generic fp32 GEMM: C[M,N] = A[M,K] @ B[K,N], all row-major ----------------
// 64x64 tile, BK=16, 256 threads, 4x4 microtile per thread.
__global__ __launch_bounds__(256) void gemm_f32(const float* __restrict__ A,
                                                const float* __restrict__ Bm,
                                                float* __restrict__ C,
                                                int M, int N, int K) {
    __shared__ float Ast[16][68];  // [k][m], row stride 272B = 16B-aligned, <=2-way banks
    __shared__ float Bs[16][68];   // [k][n]
    const int tid = threadIdx.x;
    const int tx = tid & 15, ty = tid >> 4;
    const int row0 = blockIdx.y * 64, col0 = blockIdx.x * 64;
    float acc[4][4] = {};

    for (int k0 = 0; k0 < K; k0 += 16) {
        {
            // A tile load: 64 rows x 16 k, one float4 per thread, stored transposed
            int r = tid >> 2, c = (tid & 3) * 4;
            const float4 av = *(const float4*)(A + (size_t)(row0 + r) * K + k0 + c);
            Ast[c + 0][r] = av.x;
            Ast[c + 1][r] = av.y;
            Ast[c + 2][r] = av.z;
            Ast[c + 3][r] = av.w;
            // B tile load: 16 k x 64 cols, one float4 per thread
            int rb = tid >> 4, cb = (tid & 15) * 4;
            *(float4*)&Bs[rb][cb] =
                *(const float4*)(Bm + (size_t)(k0 + rb) * N + col0 + cb);
        }
        __syncthreads();
#pragma unroll
        for (int kk = 0; kk < 16; ++kk) {
            float4 a4 = *(const float4*)&Ast[kk][ty * 4];
            float4 b4 = *(const float4*)&Bs[kk][tx * 4];
            float av[4] = {a4.x, a4.y, a4.z, a4.w};
            float bv[4] = {b4.x, b4.y, b4.z, b4.w};
#pragma unroll
            for (int i = 0; i < 4; ++i)
#pragma unroll
                for (int j = 0; j < 4; ++j)
                    acc[i][j] = fmaf(av[i], bv[j], acc[i][j]);
        }
        __syncthreads();
    }
#pragma unroll
    for (int i = 0; i < 4; ++i) {
        float4 o = {acc[i][0], acc[i][1], acc[i][2], acc[i][3]};
        *(float4*)(C + (size_t)(row0 + ty * 4 + i) * N + col0 + tx * 4) = o;
    }
}

// ---------------- RoPE (interleaved pairs) + RMSNorm over head_dim=64, in place ----------------
// one wave (64 lanes) per (row, head); 4 per 256-thread block
__global__ __launch_bounds__(256) void rope_rmsnorm(float* __restrict__ X,
                                                    const float* __restrict__ w,
                                                    int heads, int ld) {
    const int pair = blockIdx.x * 4 + (threadIdx.x >> 6);
    const int lane = threadIdx.x & 63;
    const int row = pair / heads;          // b*T + t
    const int h = pair - row * heads;
    const int t = row & (T_ - 1);

    float* px = X + (size_t)row * ld + h * HD_ + lane;
    float x = *px;

    const int p = lane >> 1;
    // inv_freq = 10000^(-p/32); angle computed in fp64 for range safety
    double inv = exp((double)p * (-9.210340371976184 / 32.0));
    double fr = (double)t * inv;
    float s = (float)sin(fr), c = (float)cos(fr);

    float other = __shfl_xor(x, 1, 64);
    // even lane: x1*c - x2*s ; odd lane: x1*s + x2*c
    float r = (lane & 1) ? fmaf(other, s, x * c) : fmaf(x, c, -(other * s));

    float sq = r * r;
#pragma unroll
    for (int off = 32; off >= 1; off >>= 1) sq += __shfl_xor(sq, off, 64);
    float invn = rsqrtf(sq * (1.0f / 64.0f) + 1e-6f);
    *px = r * invn * w[lane];
}

// ---------------- causal grouped flash attention, fp32 ----------------
// grid: (T/64, NH, B); block 256. Each block: 64 q rows of one head.
// thread (r = tid&63, dg = tid>>6) owns O[r][dg*16 .. dg*16+15].
__global__ __launch_bounds__(256) void attn_fwd(const float* __restrict__ Q,
                                                const float* __restrict__ K,
                                                const float* __restrict__ V,
                                                float* __restrict__ ctx) {
    const int qt = blockIdx.x;
    const int h  = blockIdx.y;
    const int b  = blockIdx.z;
    const int kh = h >> 2;   // h / G
    const int tid = threadIdx.x;
    const int r = tid & 63, dg = tid >> 6;

    __shared__ float Qs[64][65], Ks[64][65], Vs[64][65], Ps[64][65];
    __shared__ float mrow[64], lrow[64], corr[64];

    {
        int lr = tid >> 2, lc = (tid & 3) * 16;
        const float* src = Q + (size_t)(b * T_ + qt * 64 + lr) * (NH_ * HD_) + h * HD_ + lc;
#pragma unroll
        for (int i = 0; i < 16; ++i) Qs[lr][lc + i] = src[i];
    }
    if (tid < 64) { mrow[tid] = -3.0e38f; lrow[tid] = 0.0f; }
    float acc[16] = {};
    const int qg = qt * 64 + r;
    __syncthreads();

    for (int kt = 0; kt <= qt; ++kt) {
        {
            int lr = tid >> 2, lc = (tid & 3) * 16;
            const size_t kvoff = (size_t)(b * T_ + kt * 64 + lr) * (KH_ * HD_) + kh * HD_ + lc;
            const float* ksrc = K + kvoff;
            const float* vsrc = V + kvoff;
#pragma unroll
            for (int i = 0; i < 16; ++i) Ks[lr][lc + i] = ksrc[i];
#pragma unroll
            for (int i = 0; i < 16; ++i) Vs[lr][lc + i] = vsrc[i];
        }
        __syncthreads();

        // scores: S[r][dg*16+j] = Q[r,:] . K[c,:]
        float s[16] = {};
#pragma unroll 8
        for (int d = 0; d < 64; ++d) {
            float qv = Qs[r][d];
#pragma unroll
            for (int j = 0; j < 16; ++j)
                s[j] = fmaf(qv, Ks[dg * 16 + j][d], s[j]);
        }
#pragma unroll
        for (int j = 0; j < 16; ++j) {
            int kgj = kt * 64 + dg * 16 + j;
            Ps[r][dg * 16 + j] = (kgj <= qg) ? s[j] * 0.125f : -3.0e38f;
        }
        __syncthreads();

        // online softmax, one owner thread per row
        if (tid < 64) {
            float mold = mrow[tid];
            float mx = mold;
            for (int c2 = 0; c2 < 64; ++c2) mx = fmaxf(mx, Ps[tid][c2]);
            float cr = __expf(mold - mx);
            float sum = 0.f;
            for (int c2 = 0; c2 < 64; ++c2) {
                float pv = __expf(Ps[tid][c2] - mx);
                Ps[tid][c2] = pv;
                sum += pv;
            }
            lrow[tid] = lrow[tid] * cr + sum;
            mrow[tid] = mx;
            corr[tid] = cr;
        }
        __syncthreads();

        float cr = corr[r];
#pragma unroll
        for (int i = 0; i < 16; ++i) acc[i] *= cr;
#pragma unroll 4
        for (int c2 = 0; c2 < 64; ++c2) {
            float pv = Ps[r][c2];
#pragma unroll
            for (int i = 0; i < 16; ++i)
                acc[i] = fmaf(pv, Vs[c2][dg * 16 + i], acc[i]);
        }
        __syncthreads();
    }

    float linv = 1.0f / lrow[r];
    float* dst = ctx + (size_t)(b * T_ + qt * 64 + r) * (NH_ * HD_) + h * HD_ + dg * 16;
#pragma unroll
    for (int i = 0; i < 16; ++i) dst[i] = acc[i] * linv;
}

// ---------------- launch ----------------
extern "C" void kernel_launch(void* const* d_in, const int* in_sizes, int n_in,
                              void* d_out, int out_size, void* d_ws, size_t ws_size,
                              hipStream_t stream) {
    const float* hs = (const float*)d_in[0];
    const float* wq = (const float*)d_in[1];
    const float* wk = (const float*)d_in[2];
    const float* wv = (const float*)d_in[3];
    const float* wo = (const float*)d_in[4];
    const float* qnw = (const float*)d_in[5];
    const float* knw = (const float*)d_in[6];
    float* out = (float*)d_out;

    float* q   = (float*)d_ws;                     // [B*T, NH*HD]  8.4M floats
    float* k   = q  + (size_t)B_ * T_ * NH_ * HD_; // [B*T, KH*HD]  2.1M
    float* v   = k  + (size_t)B_ * T_ * KH_ * HD_; // [B*T, KH*HD]  2.1M
    float* ctx = v  + (size_t)B_ * T_ * KH_ * HD_; // [B*T, NH*HD]  8.4M

    const int M = B_ * T_;
    dim3 blk(256);

    gemm_f32<<<dim3((NH_ * HD_) / 64, M / 64), blk, 0, stream>>>(hs, wq, q, M, NH_ * HD_, HID_);
    gemm_f32<<<dim3((KH_ * HD_) / 64, M / 64), blk, 0, stream>>>(hs, wk, k, M, KH_ * HD_, HID_);
    gemm_f32<<<dim3((KH_ * HD_) / 64, M / 64), blk, 0, stream>>>(hs, wv, v, M, KH_ * HD_, HID_);

    rope_rmsnorm<<<(M * NH_) / 4, blk, 0, stream>>>(q, qnw, NH_, NH_ * HD_);
    rope_rmsnorm<<<(M * KH_) / 4, blk, 0, stream>>>(k, knw, KH_, KH_ * HD_);

    attn_fwd<<<dim3(T_ / 64, NH_, B_), blk, 0, stream>>>(q, k, v, ctx);

    gemm_f32<<<dim3(HID_ / 64, M / 64), blk, 0, stream>>>(ctx, wo, out, M, HID_, HID_);
}

// Round 3
// 644.238 us; speedup vs baseline: 5.5900x; 5.5900x over previous
//
#include <hip/hip_runtime.h>
#include <math.h>
#include <stdint.h>

#define B_   2
#define T_   2048
#define HID_ 2048
#define NH_  32
#define KH_  8
#define HD_  64
#define LDQKV 3072

typedef unsigned short u16;
typedef __attribute__((ext_vector_type(8))) short v8s;
typedef __attribute__((ext_vector_type(4))) float v4f;

__device__ inline v4f mfma16(v8s a, v8s b, v4f c) {
    return __builtin_amdgcn_mfma_f32_16x16x32_bf16(a, b, c, 0, 0, 0);
}
__device__ inline u16 f2bf(float f) {
    uint32_t u = __float_as_uint(f);
    u += 0x7fff + ((u >> 16) & 1);
    return (u16)(u >> 16);
}
__device__ inline float bf2f(u16 h) { return __uint_as_float(((uint32_t)h) << 16); }

// global -> LDS direct (16B per lane). LDS base must be wave-uniform.
#define GLDS(g, s)                                                                     \
    __builtin_amdgcn_global_load_lds(                                                  \
        (const __attribute__((address_space(1))) uint32_t*)(uintptr_t)(g),             \
        (__attribute__((address_space(3))) uint32_t*)(uint32_t)(uintptr_t)(s), 16, 0, 0)

// ---------------- fp32 -> bf16 elementwise ----------------
__global__ __launch_bounds__(256) void conv_f32_bf16(const float* __restrict__ in,
                                                     u16* __restrict__ out, int n4) {
    int i = blockIdx.x * 256 + threadIdx.x;
    if (i >= n4) return;
    float4 v = ((const float4*)in)[i];
    ushort4 o = {f2bf(v.x), f2bf(v.y), f2bf(v.z), f2bf(v.w)};
    ((ushort4*)out)[i] = o;
}

// ---------------- fp32 [R][C] -> bf16 [C][R] transpose-convert ----------------
__global__ __launch_bounds__(256) void trconv(const float* __restrict__ in,
                                              u16* __restrict__ out, int R, int C) {
    __shared__ float t[64][65];
    const int tid = threadIdx.x;
    const int r0 = blockIdx.y * 64, c0 = blockIdx.x * 64;
#pragma unroll
    for (int i = 0; i < 16; ++i) {
        int idx = i * 256 + tid, r = idx >> 6, c = idx & 63;
        t[r][c] = in[(size_t)(r0 + r) * C + c0 + c];
    }
    __syncthreads();
#pragma unroll
    for (int i = 0; i < 16; ++i) {
        int idx = i * 256 + tid, r = idx >> 6, c = idx & 63;
        out[(size_t)(c0 + r) * R + r0 + c] = f2bf(t[c][r]);
    }
}

// ---------------- rope sin/cos table [T][32] ----------------
__global__ __launch_bounds__(256) void rope_table(float2* __restrict__ tab) {
    int i = blockIdx.x * 256 + threadIdx.x;   // < T*32
    int t = i >> 5, p = i & 31;
    float fr = (float)t * exp2f((float)p * (-13.28771237954945f / 32.0f));
    float2 sc; sc.x = sinf(fr); sc.y = cosf(fr);
    tab[i] = sc;
}

// ---------------- bf16 GEMM: C[M,N] = A[M,K] * Bt[N,K]^T (m97 structure) ----------------
template <bool OBF>
__global__ __launch_bounds__(256) void gemm_mfma(const u16* __restrict__ A,
                                                 const u16* __restrict__ Bt,
                                                 void* __restrict__ Cv,
                                                 int M, int N, int K) {
    __shared__ __align__(16) u16 Al[128 * 32];
    __shared__ __align__(16) u16 Bl[128 * 32];
    const int tid = threadIdx.x;
    const int l = tid & 63;
    const int wid = tid >> 6;
    const int wr = wid >> 1, wc = wid & 1;
    const int lr = l & 15, lg = l >> 4;
    const int row0 = blockIdx.y * 128, col0 = blockIdx.x * 128;

    v4f acc[4][4];
    const v4f Z4 = {0.f, 0.f, 0.f, 0.f};
#pragma unroll
    for (int i = 0; i < 4; ++i)
#pragma unroll
        for (int j = 0; j < 4; ++j) acc[i][j] = Z4;

    // staging map: unit u in [0,512): chunk = u>>7 (8 k-elems), m = u&127
    const int m0 = tid & 127;
    const int ch0 = tid >> 7, ch1 = (256 + tid) >> 7;
    const u16* ga0 = A + (size_t)(row0 + m0) * K + ch0 * 8;
    const u16* ga1 = A + (size_t)(row0 + m0) * K + ch1 * 8;
    const u16* gb0 = Bt + (size_t)(col0 + m0) * K + ch0 * 8;
    const u16* gb1 = Bt + (size_t)(col0 + m0) * K + ch1 * 8;
    const int wbase = __builtin_amdgcn_readfirstlane(tid & 192);
    u16* la0 = &Al[wbase * 8];
    u16* la1 = &Al[(256 + wbase) * 8];
    u16* lb0 = &Bl[wbase * 8];
    u16* lb1 = &Bl[(256 + wbase) * 8];

    for (int k0 = 0; k0 < K; k0 += 32) {
        __syncthreads();
        GLDS(ga0 + k0, la0);
        GLDS(ga1 + k0, la1);
        GLDS(gb0 + k0, lb0);
        GLDS(gb1 + k0, lb1);
        __syncthreads();
        v8s af[4], bfr[4];
#pragma unroll
        for (int i = 0; i < 4; ++i) {
            af[i]  = *(const v8s*)&Al[(lg * 128 + wr * 64 + i * 16 + lr) * 8];
            bfr[i] = *(const v8s*)&Bl[(lg * 128 + wc * 64 + i * 16 + lr) * 8];
        }
#pragma unroll
        for (int i = 0; i < 4; ++i)
#pragma unroll
            for (int j = 0; j < 4; ++j) acc[i][j] = mfma16(af[i], bfr[j], acc[i][j]);
    }

#pragma unroll
    for (int i = 0; i < 4; ++i)
#pragma unroll
        for (int j = 0; j < 4; ++j)
#pragma unroll
            for (int r = 0; r < 4; ++r) {
                int row = row0 + wr * 64 + i * 16 + lg * 4 + r;
                int col = col0 + wc * 64 + j * 16 + lr;
                float v = acc[i][j][r];
                if (OBF) ((u16*)Cv)[(size_t)row * N + col] = f2bf(v);
                else     ((float*)Cv)[(size_t)row * N + col] = v;
            }
}

// ---------------- RoPE + RMSNorm, bf16 in-place ----------------
__global__ __launch_bounds__(256) void rope_rms(u16* __restrict__ X, const float* __restrict__ w,
                                                const float2* __restrict__ tab, int heads, int ld) {
    const int pair = blockIdx.x * 4 + (threadIdx.x >> 6);
    const int lane = threadIdx.x & 63;
    const int row = pair / heads;
    const int h = pair - row * heads;
    const int t = row & (T_ - 1);

    u16* px = X + (size_t)row * ld + h * HD_ + lane;
    float x = bf2f(*px);
    float2 sc = tab[t * 32 + (lane >> 1)];
    float other = __shfl_xor(x, 1, 64);
    float r = (lane & 1) ? fmaf(other, sc.x, x * sc.y) : fmaf(x, sc.y, -(other * sc.x));
    float sq = r * r;
#pragma unroll
    for (int off = 32; off >= 1; off >>= 1) sq += __shfl_xor(sq, off, 64);
    float invn = rsqrtf(sq * (1.0f / 64.0f) + 1e-6f);
    *px = f2bf(r * invn * w[lane]);
}

// ---------------- MFMA flash attention (causal, GQA) ----------------
// grid (T/64, NH, B), block 256 = 4 waves; wave w owns q-rows [qt*64+w*16, +16)
__global__ __launch_bounds__(256) void attn_mfma(const u16* __restrict__ Qb,
                                                 const u16* __restrict__ Kb,
                                                 const u16* __restrict__ Vb,
                                                 u16* __restrict__ Ctx) {
    const int qt = gridDim.x - 1 - blockIdx.x;   // big tiles first
    const int h = blockIdx.y, b = blockIdx.z;
    const int kh = h >> 2;
    const int tid = threadIdx.x, w = tid >> 6, l = tid & 63;
    const int lr = l & 15, lg = l >> 4;

    __shared__ __align__(16) u16 Kl[64][72];
    __shared__ __align__(16) u16 Vt[64][72];
    __shared__ __align__(16) u16 Ps[4][16][72];

    v8s qf0, qf1;
    {
        const u16* qp = Qb + (size_t)(b * T_ + qt * 64 + w * 16 + lr) * LDQKV + h * HD_ + lg * 8;
        qf0 = *(const v8s*)qp;
        qf1 = *(const v8s*)(qp + 32);
    }
    const v4f Z4 = {0.f, 0.f, 0.f, 0.f};
    v4f o[4];
    float mrun[4], lrun[4];
#pragma unroll
    for (int d = 0; d < 4; ++d) o[d] = Z4;
#pragma unroll
    for (int r = 0; r < 4; ++r) { mrun[r] = -3.0e38f; lrun[r] = 0.f; }

    for (int kt = 0; kt <= qt; ++kt) {
        __syncthreads();
        // stage K (vector) and V (transposed) tiles
#pragma unroll
        for (int ci = 0; ci < 2; ++ci) {
            int c = ci * 256 + tid;
            int kr = c >> 3, cc = (c & 7) * 8;
            const size_t roff = (size_t)(b * T_ + kt * 64 + kr) * LDQKV + kh * HD_ + cc;
            *(v8s*)&Kl[kr][cc] = *(const v8s*)(Kb + roff);
            v8s vv = *(const v8s*)(Vb + roff);
#pragma unroll
            for (int j = 0; j < 8; ++j) Vt[cc + j][kr] = (u16)vv[j];
        }
        __syncthreads();

        // S = Q K^T
        v4f s[4];
#pragma unroll
        for (int j = 0; j < 4; ++j) s[j] = Z4;
#pragma unroll
        for (int ks = 0; ks < 2; ++ks) {
            v8s a = ks ? qf1 : qf0;
#pragma unroll
            for (int j = 0; j < 4; ++j)
                s[j] = mfma16(a, *(const v8s*)&Kl[j * 16 + lr][ks * 32 + lg * 8], s[j]);
        }
        // scale + causal mask (only diagonal tile needs it)
#pragma unroll
        for (int j = 0; j < 4; ++j)
#pragma unroll
            for (int r = 0; r < 4; ++r) {
                float sv = s[j][r] * 0.125f;
                if (kt == qt && (j * 16 + lr) > (w * 16 + lg * 4 + r)) sv = -3.0e38f;
                s[j][r] = sv;
            }

        // online softmax (rows are (lg*4+r); reduce across the 16 lanes lr)
        float mx[4], corr[4], rs[4];
#pragma unroll
        for (int r = 0; r < 4; ++r)
            mx[r] = fmaxf(fmaxf(s[0][r], s[1][r]), fmaxf(s[2][r], s[3][r]));
#pragma unroll
        for (int off = 8; off >= 1; off >>= 1)
#pragma unroll
            for (int r = 0; r < 4; ++r) mx[r] = fmaxf(mx[r], __shfl_xor(mx[r], off, 64));
#pragma unroll
        for (int r = 0; r < 4; ++r) {
            float mn = fmaxf(mrun[r], mx[r]);
            corr[r] = __expf(mrun[r] - mn);
            mrun[r] = mn;
            rs[r] = 0.f;
        }
#pragma unroll
        for (int j = 0; j < 4; ++j)
#pragma unroll
            for (int r = 0; r < 4; ++r) {
                float p = __expf(s[j][r] - mrun[r]);
                rs[r] += p;
                Ps[w][lg * 4 + r][j * 16 + lr] = f2bf(p);
            }
#pragma unroll
        for (int off = 8; off >= 1; off >>= 1)
#pragma unroll
            for (int r = 0; r < 4; ++r) rs[r] += __shfl_xor(rs[r], off, 64);
#pragma unroll
        for (int r = 0; r < 4; ++r) lrun[r] = lrun[r] * corr[r] + rs[r];
#pragma unroll
        for (int d = 0; d < 4; ++d)
#pragma unroll
            for (int r = 0; r < 4; ++r) o[d][r] *= corr[r];

        // O += P V
#pragma unroll
        for (int ks = 0; ks < 2; ++ks) {
            v8s pf = *(const v8s*)&Ps[w][lr][ks * 32 + lg * 8];
#pragma unroll
            for (int d = 0; d < 4; ++d)
                o[d] = mfma16(pf, *(const v8s*)&Vt[d * 16 + lr][ks * 32 + lg * 8], o[d]);
        }
    }

#pragma unroll
    for (int r = 0; r < 4; ++r) {
        float inv = 1.0f / lrun[r];
        u16* cp = Ctx + (size_t)(b * T_ + qt * 64 + w * 16 + lg * 4 + r) * (NH_ * HD_) + h * HD_ + lr;
#pragma unroll
        for (int d = 0; d < 4; ++d) cp[d * 16] = f2bf(o[d][r] * inv);
    }
}

// ---------------- launch ----------------
extern "C" void kernel_launch(void* const* d_in, const int* in_sizes, int n_in,
                              void* d_out, int out_size, void* d_ws, size_t ws_size,
                              hipStream_t stream) {
    const float* hs  = (const float*)d_in[0];
    const float* wq  = (const float*)d_in[1];
    const float* wk  = (const float*)d_in[2];
    const float* wv  = (const float*)d_in[3];
    const float* wo  = (const float*)d_in[4];
    const float* qnw = (const float*)d_in[5];
    const float* knw = (const float*)d_in[6];
    float* out = (float*)d_out;
    (void)in_sizes; (void)n_in; (void)out_size; (void)ws_size;

    char* p = (char*)d_ws;
    auto alloc = [&](size_t bytes) { void* r = (void*)p; p += (bytes + 255) & ~(size_t)255; return r; };
    u16* hsb   = (u16*)alloc((size_t)4096 * 2048 * 2);
    u16* wqkvt = (u16*)alloc((size_t)3072 * 2048 * 2);   // [wq^T ; wk^T ; wv^T]
    u16* qkvb  = (u16*)alloc((size_t)4096 * 3072 * 2);   // [q | k | v]
    u16* wot   = (u16*)alloc((size_t)2048 * 2048 * 2);
    u16* ctx   = (u16*)alloc((size_t)4096 * 2048 * 2);
    float2* tab = (float2*)alloc((size_t)T_ * 32 * sizeof(float2));

    conv_f32_bf16<<<(4096 * 2048 / 4 + 255) / 256, 256, 0, stream>>>(hs, hsb, 4096 * 2048 / 4);
    trconv<<<dim3(2048 / 64, 2048 / 64), 256, 0, stream>>>(wq, wqkvt, 2048, 2048);
    trconv<<<dim3(512 / 64, 2048 / 64), 256, 0, stream>>>(wk, wqkvt + (size_t)2048 * 2048, 2048, 512);
    trconv<<<dim3(512 / 64, 2048 / 64), 256, 0, stream>>>(wv, wqkvt + (size_t)2560 * 2048, 2048, 512);
    trconv<<<dim3(2048 / 64, 2048 / 64), 256, 0, stream>>>(wo, wot, 2048, 2048);
    rope_table<<<(T_ * 32) / 256, 256, 0, stream>>>(tab);

    gemm_mfma<true><<<dim3(3072 / 128, 4096 / 128), 256, 0, stream>>>(hsb, wqkvt, qkvb, 4096, 3072, 2048);

    rope_rms<<<(4096 * 32) / 4, 256, 0, stream>>>(qkvb, qnw, tab, NH_, LDQKV);
    rope_rms<<<(4096 * 8) / 4, 256, 0, stream>>>(qkvb + 2048, knw, tab, KH_, LDQKV);

    attn_mfma<<<dim3(T_ / 64, NH_, B_), 256, 0, stream>>>(qkvb, qkvb + 2048, qkvb + 2560, ctx);

    gemm_mfma<false><<<dim3(2048 / 128, 4096 / 128), 256, 0, stream>>>(ctx, wot, out, 4096, 2048, 2048);
}

// Round 5
// 546.729 us; speedup vs baseline: 6.5870x; 1.1783x over previous
//
#include <hip/hip_runtime.h>
#include <math.h>
#include <stdint.h>

#define B_   2
#define T_   2048
#define HID_ 2048
#define NH_  32
#define KH_  8
#define HD_  64
#define LDQKV 3072

typedef unsigned short u16;
typedef __attribute__((ext_vector_type(8))) short v8s;
typedef __attribute__((ext_vector_type(4))) float v4f;

__device__ inline v4f mfma16(v8s a, v8s b, v4f c) {
    return __builtin_amdgcn_mfma_f32_16x16x32_bf16(a, b, c, 0, 0, 0);
}
__device__ inline u16 f2bf(float f) {
    uint32_t u = __float_as_uint(f);
    u += 0x7fff + ((u >> 16) & 1);
    return (u16)(u >> 16);
}
__device__ inline float bf2f(u16 h) { return __uint_as_float(((uint32_t)h) << 16); }

// global -> LDS direct (16B per lane). LDS base must be wave-uniform.
#define GLDS(g, s)                                                                     \
    __builtin_amdgcn_global_load_lds(                                                  \
        (const __attribute__((address_space(1))) uint32_t*)(uintptr_t)(g),             \
        (__attribute__((address_space(3))) uint32_t*)(uint32_t)(uintptr_t)(s), 16, 0, 0)

// ---------------- fp32 -> bf16 elementwise ----------------
__global__ __launch_bounds__(256) void conv_f32_bf16(const float* __restrict__ in,
                                                     u16* __restrict__ out, int n4) {
    int i = blockIdx.x * 256 + threadIdx.x;
    if (i >= n4) return;
    float4 v = ((const float4*)in)[i];
    ushort4 o = {f2bf(v.x), f2bf(v.y), f2bf(v.z), f2bf(v.w)};
    ((ushort4*)out)[i] = o;
}

// ---------------- fp32 [R][C] -> bf16 [C][R] transpose-convert ----------------
__global__ __launch_bounds__(256) void trconv(const float* __restrict__ in,
                                              u16* __restrict__ out, int R, int C) {
    __shared__ float t[64][65];
    const int tid = threadIdx.x;
    const int r0 = blockIdx.y * 64, c0 = blockIdx.x * 64;
#pragma unroll
    for (int i = 0; i < 16; ++i) {
        int idx = i * 256 + tid, r = idx >> 6, c = idx & 63;
        t[r][c] = in[(size_t)(r0 + r) * C + c0 + c];
    }
    __syncthreads();
#pragma unroll
    for (int i = 0; i < 16; ++i) {
        int idx = i * 256 + tid, r = idx >> 6, c = idx & 63;
        out[(size_t)(c0 + r) * R + r0 + c] = f2bf(t[c][r]);
    }
}

// ---------------- rope sin/cos table [T][32] ----------------
__global__ __launch_bounds__(256) void rope_table(float2* __restrict__ tab) {
    int i = blockIdx.x * 256 + threadIdx.x;   // < T*32
    int t = i >> 5, p = i & 31;
    float fr = (float)t * exp2f((float)p * (-13.28771237954945f / 32.0f));
    float2 sc; sc.x = sinf(fr); sc.y = cosf(fr);
    tab[i] = sc;
}

// ---------------- V [B*T, KH*HD] (stride LDQKV) -> Vt [B][KH][HD][T] bf16 ----------------
__global__ __launch_bounds__(256) void vtrans(const u16* __restrict__ V, u16* __restrict__ Vt) {
    const int t0 = blockIdx.x * 64, kh = blockIdx.y, b = blockIdx.z;
    const int tid = threadIdx.x;
    __shared__ __align__(16) u16 tl[64][72];
#pragma unroll
    for (int p = 0; p < 2; ++p) {
        int c = p * 256 + tid, trow = c >> 3, d8 = (c & 7) * 8;
        *(v8s*)&tl[trow][d8] =
            *(const v8s*)(V + (size_t)(b * T_ + t0 + trow) * LDQKV + kh * HD_ + d8);
    }
    __syncthreads();
#pragma unroll
    for (int p = 0; p < 2; ++p) {
        int c = p * 256 + tid, drow = c >> 3, t8 = (c & 7) * 8;
        v8s o;
#pragma unroll
        for (int j = 0; j < 8; ++j) o[j] = (short)tl[t8 + j][drow];
        *(v8s*)(Vt + ((size_t)((b * KH_ + kh) * HD_) + drow) * T_ + t0 + t8) = o;
    }
}

// ---------------- bf16 GEMM: C[M,N] = A[M,K] * Bt[N,K]^T (m97 structure) ----------------
template <bool OBF>
__global__ __launch_bounds__(256) void gemm_mfma(const u16* __restrict__ A,
                                                 const u16* __restrict__ Bt,
                                                 void* __restrict__ Cv,
                                                 int M, int N, int K) {
    __shared__ __align__(16) u16 Al[128 * 32];
    __shared__ __align__(16) u16 Bl[128 * 32];
    const int tid = threadIdx.x;
    const int l = tid & 63;
    const int wid = tid >> 6;
    const int wr = wid >> 1, wc = wid & 1;
    const int lr = l & 15, lg = l >> 4;
    const int row0 = blockIdx.y * 128, col0 = blockIdx.x * 128;

    v4f acc[4][4];
    const v4f Z4 = {0.f, 0.f, 0.f, 0.f};
#pragma unroll
    for (int i = 0; i < 4; ++i)
#pragma unroll
        for (int j = 0; j < 4; ++j) acc[i][j] = Z4;

    const int m0 = tid & 127;
    const int ch0 = tid >> 7, ch1 = (256 + tid) >> 7;
    const u16* ga0 = A + (size_t)(row0 + m0) * K + ch0 * 8;
    const u16* ga1 = A + (size_t)(row0 + m0) * K + ch1 * 8;
    const u16* gb0 = Bt + (size_t)(col0 + m0) * K + ch0 * 8;
    const u16* gb1 = Bt + (size_t)(col0 + m0) * K + ch1 * 8;
    const int wbase = __builtin_amdgcn_readfirstlane(tid & 192);
    u16* la0 = &Al[wbase * 8];
    u16* la1 = &Al[(256 + wbase) * 8];
    u16* lb0 = &Bl[wbase * 8];
    u16* lb1 = &Bl[(256 + wbase) * 8];

    for (int k0 = 0; k0 < K; k0 += 32) {
        __syncthreads();
        GLDS(ga0 + k0, la0);
        GLDS(ga1 + k0, la1);
        GLDS(gb0 + k0, lb0);
        GLDS(gb1 + k0, lb1);
        __syncthreads();
        v8s af[4], bfr[4];
#pragma unroll
        for (int i = 0; i < 4; ++i) {
            af[i]  = *(const v8s*)&Al[(lg * 128 + wr * 64 + i * 16 + lr) * 8];
            bfr[i] = *(const v8s*)&Bl[(lg * 128 + wc * 64 + i * 16 + lr) * 8];
        }
#pragma unroll
        for (int i = 0; i < 4; ++i)
#pragma unroll
            for (int j = 0; j < 4; ++j) acc[i][j] = mfma16(af[i], bfr[j], acc[i][j]);
    }

#pragma unroll
    for (int i = 0; i < 4; ++i)
#pragma unroll
        for (int j = 0; j < 4; ++j)
#pragma unroll
            for (int r = 0; r < 4; ++r) {
                int row = row0 + wr * 64 + i * 16 + lg * 4 + r;
                int col = col0 + wc * 64 + j * 16 + lr;
                float v = acc[i][j][r];
                if (OBF) ((u16*)Cv)[(size_t)row * N + col] = f2bf(v);
                else     ((float*)Cv)[(size_t)row * N + col] = v;
            }
}

// ---------------- RoPE + RMSNorm, bf16 in-place ----------------
__global__ __launch_bounds__(256) void rope_rms(u16* __restrict__ X, const float* __restrict__ w,
                                                const float2* __restrict__ tab, int heads, int ld) {
    const int pair = blockIdx.x * 4 + (threadIdx.x >> 6);
    const int lane = threadIdx.x & 63;
    const int row = pair / heads;
    const int h = pair - row * heads;
    const int t = row & (T_ - 1);

    u16* px = X + (size_t)row * ld + h * HD_ + lane;
    float x = bf2f(*px);
    float2 sc = tab[t * 32 + (lane >> 1)];
    float other = __shfl_xor(x, 1, 64);
    float r = (lane & 1) ? fmaf(other, sc.x, x * sc.y) : fmaf(x, sc.y, -(other * sc.x));
    float sq = r * r;
#pragma unroll
    for (int off = 32; off >= 1; off >>= 1) sq += __shfl_xor(sq, off, 64);
    float invn = rsqrtf(sq * (1.0f / 64.0f) + 1e-6f);
    *px = f2bf(r * invn * w[lane]);
}

// ---------------- MFMA flash attention (causal, GQA) ----------------
// grid (T/64, NH, B), block 256 = 4 waves; wave w owns q-rows [qt*64+w*16, +16)
// K and Vt tiles staged via global_load_lds with XOR chunk swizzle; double-buffered.
__global__ __launch_bounds__(256) void attn_mfma(const u16* __restrict__ Qb,
                                                 const u16* __restrict__ Kb,
                                                 const u16* __restrict__ VTb,
                                                 u16* __restrict__ Ctx) {
    const int qt = gridDim.x - 1 - blockIdx.x;   // big tiles first
    const int h = blockIdx.y, b = blockIdx.z;
    const int kh = h >> 2;
    const int tid = threadIdx.x, w = tid >> 6, l = tid & 63;
    const int lr = l & 15, lg = l >> 4;

    __shared__ __align__(16) u16 Kbuf[2][64 * 64];
    __shared__ __align__(16) u16 Vbuf[2][64 * 64];
    __shared__ __align__(16) u16 Ps[4][16][72];

    // Q fragments (registers)
    v8s qf0, qf1;
    {
        const u16* qp = Qb + (size_t)(b * T_ + qt * 64 + w * 16 + lr) * LDQKV + h * HD_ + lg * 8;
        qf0 = *(const v8s*)qp;
        qf1 = *(const v8s*)(qp + 32);
    }

    // staging geometry: wave w stages rows [w*16, w*16+16) of each tile, 2 passes of 64 chunks
    const int wu = __builtin_amdgcn_readfirstlane(w);
    const int srow = w * 16 + (l >> 3);          // pass0 row; pass1 = srow+8
    const int sc16 = (l & 7) ^ (srow & 7);       // swizzled source chunk (same both passes)
    const u16* kg_base = Kb + (size_t)(b * T_ + srow) * LDQKV + kh * HD_ + sc16 * 8;
    const u16* vg_base = VTb + ((size_t)((b * KH_ + kh) * HD_) + srow) * T_ + sc16 * 8;

    const v4f Z4 = {0.f, 0.f, 0.f, 0.f};
    v4f o[4];
    float mrun[4], lrun[4];
#pragma unroll
    for (int d = 0; d < 4; ++d) o[d] = Z4;
#pragma unroll
    for (int r = 0; r < 4; ++r) { mrun[r] = -3.0e38f; lrun[r] = 0.f; }

    auto stage = [&](int buf, int kt) {
        u16* kl = &Kbuf[buf][wu * 1024];
        u16* vl = &Vbuf[buf][wu * 1024];
        const u16* kg = kg_base + (size_t)kt * 64 * LDQKV;
        const u16* vg = vg_base + kt * 64;
        GLDS(kg, kl);
        GLDS(kg + 8 * LDQKV, kl + 512);
        GLDS(vg, vl);
        GLDS(vg + 8 * T_, vl + 512);
    };

    stage(0, 0);
    int buf = 0;
    const int fr_swz = lr & 7;

    for (int kt = 0; kt <= qt; ++kt) {
        if (kt < qt) {
            stage(buf ^ 1, kt + 1);
            asm volatile("s_waitcnt vmcnt(4)" ::: "memory");
        } else {
            asm volatile("s_waitcnt vmcnt(0)" ::: "memory");
        }
        __builtin_amdgcn_s_barrier();

        const u16* Kc = Kbuf[buf];
        const u16* Vc = Vbuf[buf];

        // S = Q K^T
        v4f s[4];
#pragma unroll
        for (int j = 0; j < 4; ++j) s[j] = Z4;
#pragma unroll
        for (int ks = 0; ks < 2; ++ks) {
            v8s a = ks ? qf1 : qf0;
#pragma unroll
            for (int j = 0; j < 4; ++j)
                s[j] = mfma16(a, *(const v8s*)&Kc[(j * 16 + lr) * 64 + (((ks * 4 + lg) ^ fr_swz) * 8)],
                              s[j]);
        }
        // scale + causal mask (only diagonal tile)
#pragma unroll
        for (int j = 0; j < 4; ++j)
#pragma unroll
            for (int r = 0; r < 4; ++r) {
                float sv = s[j][r] * 0.125f;
                if (kt == qt && (j * 16 + lr) > (w * 16 + lg * 4 + r)) sv = -3.0e38f;
                s[j][r] = sv;
            }

        // online softmax (rows lg*4+r; reduce across 16 lanes lr)
        float mx[4], corr[4], rs[4];
#pragma unroll
        for (int r = 0; r < 4; ++r)
            mx[r] = fmaxf(fmaxf(s[0][r], s[1][r]), fmaxf(s[2][r], s[3][r]));
#pragma unroll
        for (int off = 8; off >= 1; off >>= 1)
#pragma unroll
            for (int r = 0; r < 4; ++r) mx[r] = fmaxf(mx[r], __shfl_xor(mx[r], off, 64));
#pragma unroll
        for (int r = 0; r < 4; ++r) {
            float mn = fmaxf(mrun[r], mx[r]);
            corr[r] = __expf(mrun[r] - mn);
            mrun[r] = mn;
            rs[r] = 0.f;
        }
#pragma unroll
        for (int j = 0; j < 4; ++j)
#pragma unroll
            for (int r = 0; r < 4; ++r) {
                float p = __expf(s[j][r] - mrun[r]);
                rs[r] += p;
                Ps[w][lg * 4 + r][j * 16 + lr] = f2bf(p);
            }
#pragma unroll
        for (int off = 8; off >= 1; off >>= 1)
#pragma unroll
            for (int r = 0; r < 4; ++r) rs[r] += __shfl_xor(rs[r], off, 64);
#pragma unroll
        for (int r = 0; r < 4; ++r) lrun[r] = lrun[r] * corr[r] + rs[r];
#pragma unroll
        for (int d = 0; d < 4; ++d)
#pragma unroll
            for (int r = 0; r < 4; ++r) o[d][r] *= corr[r];

        // Ps written by this wave's lanes; ensure visible before cross-lane frag reads
        asm volatile("s_waitcnt lgkmcnt(0)" ::: "memory");

        // O += P V (B-frag from swizzled Vt tile: rows = d, cols = k)
#pragma unroll
        for (int ks = 0; ks < 2; ++ks) {
            v8s pf = *(const v8s*)&Ps[w][lr][ks * 32 + lg * 8];
#pragma unroll
            for (int d = 0; d < 4; ++d)
                o[d] = mfma16(pf, *(const v8s*)&Vc[(d * 16 + lr) * 64 + (((ks * 4 + lg) ^ fr_swz) * 8)],
                              o[d]);
        }

        asm volatile("s_waitcnt lgkmcnt(0)" ::: "memory");
        __builtin_amdgcn_s_barrier();   // all waves done reading buf -> reusable
        buf ^= 1;
    }

#pragma unroll
    for (int r = 0; r < 4; ++r) {
        float inv = 1.0f / lrun[r];
        u16* cp = Ctx + (size_t)(b * T_ + qt * 64 + w * 16 + lg * 4 + r) * (NH_ * HD_) + h * HD_ + lr;
#pragma unroll
        for (int d = 0; d < 4; ++d) cp[d * 16] = f2bf(o[d][r] * inv);
    }
}

// ---------------- launch ----------------
extern "C" void kernel_launch(void* const* d_in, const int* in_sizes, int n_in,
                              void* d_out, int out_size, void* d_ws, size_t ws_size,
                              hipStream_t stream) {
    const float* hs  = (const float*)d_in[0];
    const float* wq  = (const float*)d_in[1];
    const float* wk  = (const float*)d_in[2];
    const float* wv  = (const float*)d_in[3];
    const float* wo  = (const float*)d_in[4];
    const float* qnw = (const float*)d_in[5];
    const float* knw = (const float*)d_in[6];
    float* out = (float*)d_out;
    (void)in_sizes; (void)n_in; (void)out_size; (void)ws_size;

    char* p = (char*)d_ws;
    auto alloc = [&](size_t bytes) { void* r = (void*)p; p += (bytes + 255) & ~(size_t)255; return r; };
    u16* hsb   = (u16*)alloc((size_t)4096 * 2048 * 2);
    u16* wqkvt = (u16*)alloc((size_t)3072 * 2048 * 2);   // [wq^T ; wk^T ; wv^T]
    u16* qkvb  = (u16*)alloc((size_t)4096 * 3072 * 2);   // [q | k | v]
    u16* wot   = (u16*)alloc((size_t)2048 * 2048 * 2);
    u16* ctx   = (u16*)alloc((size_t)4096 * 2048 * 2);
    u16* vt    = (u16*)alloc((size_t)B_ * KH_ * HD_ * T_ * 2);
    float2* tab = (float2*)alloc((size_t)T_ * 32 * sizeof(float2));

    conv_f32_bf16<<<(4096 * 2048 / 4 + 255) / 256, 256, 0, stream>>>(hs, hsb, 4096 * 2048 / 4);
    trconv<<<dim3(2048 / 64, 2048 / 64), 256, 0, stream>>>(wq, wqkvt, 2048, 2048);
    trconv<<<dim3(512 / 64, 2048 / 64), 256, 0, stream>>>(wk, wqkvt + (size_t)2048 * 2048, 2048, 512);
    trconv<<<dim3(512 / 64, 2048 / 64), 256, 0, stream>>>(wv, wqkvt + (size_t)2560 * 2048, 2048, 512);
    trconv<<<dim3(2048 / 64, 2048 / 64), 256, 0, stream>>>(wo, wot, 2048, 2048);
    rope_table<<<(T_ * 32) / 256, 256, 0, stream>>>(tab);

    gemm_mfma<true><<<dim3(3072 / 128, 4096 / 128), 256, 0, stream>>>(hsb, wqkvt, qkvb, 4096, 3072, 2048);

    rope_rms<<<(4096 * 32) / 4, 256, 0, stream>>>(qkvb, qnw, tab, NH_, LDQKV);
    rope_rms<<<(4096 * 8) / 4, 256, 0, stream>>>(qkvb + 2048, knw, tab, KH_, LDQKV);
    vtrans<<<dim3(T_ / 64, KH_, B_), 256, 0, stream>>>(qkvb + 2560, vt);

    attn_mfma<<<dim3(T_ / 64, NH_, B_), 256, 0, stream>>>(qkvb, qkvb + 2048, vt, ctx);

    gemm_mfma<false><<<dim3(2048 / 128, 4096 / 128), 256, 0, stream>>>(ctx, wot, out, 4096, 2048, 2048);
}

// Round 6
// 456.127 us; speedup vs baseline: 7.8954x; 1.1986x over previous
//
#include <hip/hip_runtime.h>
#include <math.h>
#include <stdint.h>

#define B_   2
#define T_   2048
#define HID_ 2048
#define NH_  32
#define KH_  8
#define HD_  64
#define LDQKV 3072

typedef unsigned short u16;
typedef __attribute__((ext_vector_type(8))) short v8s;
typedef __attribute__((ext_vector_type(4))) float v4f;

__device__ inline v4f mfma16(v8s a, v8s b, v4f c) {
    return __builtin_amdgcn_mfma_f32_16x16x32_bf16(a, b, c, 0, 0, 0);
}
__device__ inline u16 f2bf(float f) {
    uint32_t u = __float_as_uint(f);
    u += 0x7fff + ((u >> 16) & 1);
    return (u16)(u >> 16);
}
__device__ inline float bf2f(u16 h) { return __uint_as_float(((uint32_t)h) << 16); }
__device__ inline uint32_t cvtpk_bf16(float lo, float hi) {
    uint32_t r;
    asm("v_cvt_pk_bf16_f32 %0, %1, %2" : "=v"(r) : "v"(lo), "v"(hi));
    return r;
}

// global -> LDS direct (16B per lane). LDS base must be wave-uniform.
#define GLDS(g, s)                                                                     \
    __builtin_amdgcn_global_load_lds(                                                  \
        (const __attribute__((address_space(1))) uint32_t*)(uintptr_t)(g),             \
        (__attribute__((address_space(3))) uint32_t*)(uint32_t)(uintptr_t)(s), 16, 0, 0)

// ---------------- fp32 -> bf16 elementwise ----------------
__global__ __launch_bounds__(256) void conv_f32_bf16(const float* __restrict__ in,
                                                     u16* __restrict__ out, int n4) {
    int i = blockIdx.x * 256 + threadIdx.x;
    if (i >= n4) return;
    float4 v = ((const float4*)in)[i];
    ushort4 o = {f2bf(v.x), f2bf(v.y), f2bf(v.z), f2bf(v.w)};
    ((ushort4*)out)[i] = o;
}

// ---------------- fp32 [R][C] -> bf16 [C][R] transpose-convert ----------------
__global__ __launch_bounds__(256) void trconv(const float* __restrict__ in,
                                              u16* __restrict__ out, int R, int C) {
    __shared__ float t[64][65];
    const int tid = threadIdx.x;
    const int r0 = blockIdx.y * 64, c0 = blockIdx.x * 64;
#pragma unroll
    for (int i = 0; i < 16; ++i) {
        int idx = i * 256 + tid, r = idx >> 6, c = idx & 63;
        t[r][c] = in[(size_t)(r0 + r) * C + c0 + c];
    }
    __syncthreads();
#pragma unroll
    for (int i = 0; i < 16; ++i) {
        int idx = i * 256 + tid, r = idx >> 6, c = idx & 63;
        out[(size_t)(c0 + r) * R + r0 + c] = f2bf(t[c][r]);
    }
}

// ---------------- rope sin/cos table [T][32] ----------------
__global__ __launch_bounds__(256) void rope_table(float2* __restrict__ tab) {
    int i = blockIdx.x * 256 + threadIdx.x;   // < T*32
    int t = i >> 5, p = i & 31;
    float fr = (float)t * exp2f((float)p * (-13.28771237954945f / 32.0f));
    float2 sc; sc.x = sinf(fr); sc.y = cosf(fr);
    tab[i] = sc;
}

// ---------------- V [B*T, KH*HD] (stride LDQKV) -> Vt [B][KH][HD][T] bf16 ----------------
__global__ __launch_bounds__(256) void vtrans(const u16* __restrict__ V, u16* __restrict__ Vt) {
    const int t0 = blockIdx.x * 64, kh = blockIdx.y, b = blockIdx.z;
    const int tid = threadIdx.x;
    __shared__ __align__(16) u16 tl[64][72];
#pragma unroll
    for (int p = 0; p < 2; ++p) {
        int c = p * 256 + tid, trow = c >> 3, d8 = (c & 7) * 8;
        *(v8s*)&tl[trow][d8] =
            *(const v8s*)(V + (size_t)(b * T_ + t0 + trow) * LDQKV + kh * HD_ + d8);
    }
    __syncthreads();
#pragma unroll
    for (int p = 0; p < 2; ++p) {
        int c = p * 256 + tid, drow = c >> 3, t8 = (c & 7) * 8;
        v8s o;
#pragma unroll
        for (int j = 0; j < 8; ++j) o[j] = (short)tl[t8 + j][drow];
        *(v8s*)(Vt + ((size_t)((b * KH_ + kh) * HD_) + drow) * T_ + t0 + t8) = o;
    }
}

// ---------------- bf16 GEMM: C[M,N] = A[M,K] * Bt[N,K]^T (m97 structure) ----------------
template <bool OBF>
__global__ __launch_bounds__(256) void gemm_mfma(const u16* __restrict__ A,
                                                 const u16* __restrict__ Bt,
                                                 void* __restrict__ Cv,
                                                 int M, int N, int K) {
    __shared__ __align__(16) u16 Al[128 * 32];
    __shared__ __align__(16) u16 Bl[128 * 32];
    const int tid = threadIdx.x;
    const int l = tid & 63;
    const int wid = tid >> 6;
    const int wr = wid >> 1, wc = wid & 1;
    const int lr = l & 15, lg = l >> 4;
    const int row0 = blockIdx.y * 128, col0 = blockIdx.x * 128;

    v4f acc[4][4];
    const v4f Z4 = {0.f, 0.f, 0.f, 0.f};
#pragma unroll
    for (int i = 0; i < 4; ++i)
#pragma unroll
        for (int j = 0; j < 4; ++j) acc[i][j] = Z4;

    const int m0 = tid & 127;
    const int ch0 = tid >> 7, ch1 = (256 + tid) >> 7;
    const u16* ga0 = A + (size_t)(row0 + m0) * K + ch0 * 8;
    const u16* ga1 = A + (size_t)(row0 + m0) * K + ch1 * 8;
    const u16* gb0 = Bt + (size_t)(col0 + m0) * K + ch0 * 8;
    const u16* gb1 = Bt + (size_t)(col0 + m0) * K + ch1 * 8;
    const int wbase = __builtin_amdgcn_readfirstlane(tid & 192);
    u16* la0 = &Al[wbase * 8];
    u16* la1 = &Al[(256 + wbase) * 8];
    u16* lb0 = &Bl[wbase * 8];
    u16* lb1 = &Bl[(256 + wbase) * 8];

    for (int k0 = 0; k0 < K; k0 += 32) {
        __syncthreads();
        GLDS(ga0 + k0, la0);
        GLDS(ga1 + k0, la1);
        GLDS(gb0 + k0, lb0);
        GLDS(gb1 + k0, lb1);
        __syncthreads();
        v8s af[4], bfr[4];
#pragma unroll
        for (int i = 0; i < 4; ++i) {
            af[i]  = *(const v8s*)&Al[(lg * 128 + wr * 64 + i * 16 + lr) * 8];
            bfr[i] = *(const v8s*)&Bl[(lg * 128 + wc * 64 + i * 16 + lr) * 8];
        }
#pragma unroll
        for (int i = 0; i < 4; ++i)
#pragma unroll
            for (int j = 0; j < 4; ++j) acc[i][j] = mfma16(af[i], bfr[j], acc[i][j]);
    }

#pragma unroll
    for (int i = 0; i < 4; ++i)
#pragma unroll
        for (int j = 0; j < 4; ++j)
#pragma unroll
            for (int r = 0; r < 4; ++r) {
                int row = row0 + wr * 64 + i * 16 + lg * 4 + r;
                int col = col0 + wc * 64 + j * 16 + lr;
                float v = acc[i][j][r];
                if (OBF) ((u16*)Cv)[(size_t)row * N + col] = f2bf(v);
                else     ((float*)Cv)[(size_t)row * N + col] = v;
            }
}

// ---------------- RoPE + RMSNorm, bf16 in-place ----------------
__global__ __launch_bounds__(256) void rope_rms(u16* __restrict__ X, const float* __restrict__ w,
                                                const float2* __restrict__ tab, int heads, int ld) {
    const int pair = blockIdx.x * 4 + (threadIdx.x >> 6);
    const int lane = threadIdx.x & 63;
    const int row = pair / heads;
    const int h = pair - row * heads;
    const int t = row & (T_ - 1);

    u16* px = X + (size_t)row * ld + h * HD_ + lane;
    float x = bf2f(*px);
    float2 sc = tab[t * 32 + (lane >> 1)];
    float other = __shfl_xor(x, 1, 64);
    float r = (lane & 1) ? fmaf(other, sc.x, x * sc.y) : fmaf(x, sc.y, -(other * sc.x));
    float sq = r * r;
#pragma unroll
    for (int off = 32; off >= 1; off >>= 1) sq += __shfl_xor(sq, off, 64);
    float invn = rsqrtf(sq * (1.0f / 64.0f) + 1e-6f);
    *px = f2bf(r * invn * w[lane]);
}

// ---------------- MFMA flash attention (causal, GQA, 4 heads/block) ----------------
// grid (T/64, KH, B), block 256 = 4 waves; wave w owns q-rows [qt*64+w*16, +16) for
// ALL 4 q-heads of kv-head kh. Swapped-operand MFMA: lane holds full q-row slices.
// Fixed-max softmax: RMSNorm => |S| <= 8, so p = exp2(S_raw*c1 + c0) with static max 8.
__global__ __launch_bounds__(256, 2) void attn_mfma(const u16* __restrict__ Qb,
                                                    const u16* __restrict__ Kb,
                                                    const u16* __restrict__ VTb,
                                                    u16* __restrict__ Ctx) {
    const int qt = gridDim.x - 1 - blockIdx.x;   // big tiles first
    const int kh = blockIdx.y, b = blockIdx.z;
    const int tid = threadIdx.x, w = tid >> 6, l = tid & 63;
    const int lr = l & 15, lg = l >> 4;          // lr: q (D/B-frags) or row (A-frags); lg: k-chunk

    __shared__ __align__(16) u16 Kbuf[2][64 * 64];
    __shared__ __align__(16) u16 Vbuf[2][64 * 64];
    __shared__ __align__(16) uint32_t Ps[4][16][36];   // [wave][q][packed col], 144B rows

    // Q fragments for the 4 grouped heads (registers)
    v8s qf[4][2];
#pragma unroll
    for (int g = 0; g < 4; ++g) {
        const u16* qp = Qb + (size_t)(b * T_ + qt * 64 + w * 16 + lr) * LDQKV +
                        (kh * 4 + g) * HD_ + lg * 8;
        qf[g][0] = *(const v8s*)qp;
        qf[g][1] = *(const v8s*)(qp + 32);
    }

    // staging geometry: wave w stages rows [w*16, +16), source-chunk XOR swizzle
    const int wu = __builtin_amdgcn_readfirstlane(w);
    const int srow = w * 16 + (l >> 3);
    const int sc16 = (l & 7) ^ (srow & 7);
    const u16* kg_base = Kb + (size_t)(b * T_ + srow) * LDQKV + kh * HD_ + sc16 * 8;
    const u16* vg_base = VTb + ((size_t)((b * KH_ + kh) * HD_) + srow) * T_ + sc16 * 8;

    const v4f Z4 = {0.f, 0.f, 0.f, 0.f};
    v4f o[4][4];
    float lsum[4];
#pragma unroll
    for (int g = 0; g < 4; ++g) {
        lsum[g] = 0.f;
#pragma unroll
        for (int d = 0; d < 4; ++d) o[g][d] = Z4;
    }

    auto stage = [&](int bufi, int kt) {
        u16* kl = &Kbuf[bufi][wu * 1024];
        u16* vl = &Vbuf[bufi][wu * 1024];
        const u16* kg = kg_base + (size_t)kt * 64 * LDQKV;
        const u16* vg = vg_base + kt * 64;
        GLDS(kg, kl);
        GLDS(kg + 8 * LDQKV, kl + 512);
        GLDS(vg, vl);
        GLDS(vg + 8 * T_, vl + 512);
    };

    const int fr_swz = lr & 7;
    const float C1 = 0.18033688011112042f;    // 0.125 * log2(e)
    const float C0 = -11.541560327111707f;    // -8 * log2(e)

    auto body = [&](const u16* Kc, const u16* Vc, bool masked) {
#pragma unroll
        for (int g = 0; g < 4; ++g) {
            // S^T = K Q^T : lane holds q-row lr, cols j*16 + lg*4 + r
            v4f s[4];
#pragma unroll
            for (int j = 0; j < 4; ++j) s[j] = Z4;
#pragma unroll
            for (int ks = 0; ks < 2; ++ks) {
#pragma unroll
                for (int j = 0; j < 4; ++j)
                    s[j] = mfma16(*(const v8s*)&Kc[(j * 16 + lr) * 64 + (((ks * 4 + lg) ^ fr_swz) * 8)],
                                  qf[g][ks], s[j]);
            }
            // p = exp2(S_raw*C1 + C0)  (== exp(S*0.125 - 8)), causal zero on diagonal tile
            uint32_t pk[4][2];
#pragma unroll
            for (int j = 0; j < 4; ++j) {
                float p[4];
#pragma unroll
                for (int r = 0; r < 4; ++r) {
                    float pv = exp2f(fmaf(s[j][r], C1, C0));
                    if (masked && (j * 16 + lg * 4 + r) > (w * 16 + lr)) pv = 0.f;
                    p[r] = pv;
                }
                lsum[g] += (p[0] + p[1]) + (p[2] + p[3]);
                pk[j][0] = cvtpk_bf16(p[0], p[1]);
                pk[j][1] = cvtpk_bf16(p[2], p[3]);
            }
            // write packed P^T rows: [q = lr][col-pair j*8 + lg*2 + rp]
#pragma unroll
            for (int j = 0; j < 4; ++j) {
                Ps[w][lr][j * 8 + lg * 2 + 0] = pk[j][0];
                Ps[w][lr][j * 8 + lg * 2 + 1] = pk[j][1];
            }
            asm volatile("s_waitcnt lgkmcnt(0)" ::: "memory");
            // O^T += V^T P^T : lane holds q = lr, d-rows dj*16 + lg*4 + r
#pragma unroll
            for (int ks = 0; ks < 2; ++ks) {
                v8s pf = *(const v8s*)&Ps[w][lr][ks * 16 + lg * 4];
#pragma unroll
                for (int dj = 0; dj < 4; ++dj)
                    o[g][dj] = mfma16(*(const v8s*)&Vc[(dj * 16 + lr) * 64 + (((ks * 4 + lg) ^ fr_swz) * 8)],
                                      pf, o[g][dj]);
            }
        }
    };

    stage(0, 0);
    int buf = 0;
    for (int kt = 0; kt < qt; ++kt) {
        stage(buf ^ 1, kt + 1);
        asm volatile("s_waitcnt vmcnt(4)" ::: "memory");
        __builtin_amdgcn_s_barrier();
        body(Kbuf[buf], Vbuf[buf], false);
        asm volatile("s_waitcnt lgkmcnt(0)" ::: "memory");
        __builtin_amdgcn_s_barrier();
        buf ^= 1;
    }
    asm volatile("s_waitcnt vmcnt(0)" ::: "memory");
    __builtin_amdgcn_s_barrier();
    body(Kbuf[buf], Vbuf[buf], true);

    // final: reduce lane-local partial sums across the 4 lg replicas of each q-row
#pragma unroll
    for (int g = 0; g < 4; ++g) {
        float t1 = lsum[g] + __shfl_xor(lsum[g], 16, 64);
        float inv = 1.0f / (t1 + __shfl_xor(t1, 32, 64));
        u16* cp = Ctx + (size_t)(b * T_ + qt * 64 + w * 16 + lr) * (NH_ * HD_) +
                  (kh * 4 + g) * HD_ + lg * 4;
#pragma unroll
        for (int dj = 0; dj < 4; ++dj) {
            ushort4 ov = {f2bf(o[g][dj][0] * inv), f2bf(o[g][dj][1] * inv),
                          f2bf(o[g][dj][2] * inv), f2bf(o[g][dj][3] * inv)};
            *(ushort4*)(cp + dj * 16) = ov;
        }
    }
}

// ---------------- launch ----------------
extern "C" void kernel_launch(void* const* d_in, const int* in_sizes, int n_in,
                              void* d_out, int out_size, void* d_ws, size_t ws_size,
                              hipStream_t stream) {
    const float* hs  = (const float*)d_in[0];
    const float* wq  = (const float*)d_in[1];
    const float* wk  = (const float*)d_in[2];
    const float* wv  = (const float*)d_in[3];
    const float* wo  = (const float*)d_in[4];
    const float* qnw = (const float*)d_in[5];
    const float* knw = (const float*)d_in[6];
    float* out = (float*)d_out;
    (void)in_sizes; (void)n_in; (void)out_size; (void)ws_size;

    char* p = (char*)d_ws;
    auto alloc = [&](size_t bytes) { void* r = (void*)p; p += (bytes + 255) & ~(size_t)255; return r; };
    u16* hsb   = (u16*)alloc((size_t)4096 * 2048 * 2);
    u16* wqkvt = (u16*)alloc((size_t)3072 * 2048 * 2);   // [wq^T ; wk^T ; wv^T]
    u16* qkvb  = (u16*)alloc((size_t)4096 * 3072 * 2);   // [q | k | v]
    u16* wot   = (u16*)alloc((size_t)2048 * 2048 * 2);
    u16* ctx   = (u16*)alloc((size_t)4096 * 2048 * 2);
    u16* vt    = (u16*)alloc((size_t)B_ * KH_ * HD_ * T_ * 2);
    float2* tab = (float2*)alloc((size_t)T_ * 32 * sizeof(float2));

    conv_f32_bf16<<<(4096 * 2048 / 4 + 255) / 256, 256, 0, stream>>>(hs, hsb, 4096 * 2048 / 4);
    trconv<<<dim3(2048 / 64, 2048 / 64), 256, 0, stream>>>(wq, wqkvt, 2048, 2048);
    trconv<<<dim3(512 / 64, 2048 / 64), 256, 0, stream>>>(wk, wqkvt + (size_t)2048 * 2048, 2048, 512);
    trconv<<<dim3(512 / 64, 2048 / 64), 256, 0, stream>>>(wv, wqkvt + (size_t)2560 * 2048, 2048, 512);
    trconv<<<dim3(2048 / 64, 2048 / 64), 256, 0, stream>>>(wo, wot, 2048, 2048);
    rope_table<<<(T_ * 32) / 256, 256, 0, stream>>>(tab);

    gemm_mfma<true><<<dim3(3072 / 128, 4096 / 128), 256, 0, stream>>>(hsb, wqkvt, qkvb, 4096, 3072, 2048);

    rope_rms<<<(4096 * 32) / 4, 256, 0, stream>>>(qkvb, qnw, tab, NH_, LDQKV);
    rope_rms<<<(4096 * 8) / 4, 256, 0, stream>>>(qkvb + 2048, knw, tab, KH_, LDQKV);
    vtrans<<<dim3(T_ / 64, KH_, B_), 256, 0, stream>>>(qkvb + 2560, vt);

    attn_mfma<<<dim3(T_ / 64, KH_, B_), 256, 0, stream>>>(qkvb, qkvb + 2048, vt, ctx);

    gemm_mfma<false><<<dim3(2048 / 128, 4096 / 128), 256, 0, stream>>>(ctx, wot, out, 4096, 2048, 2048);
}

// Round 7
// 440.681 us; speedup vs baseline: 8.1721x; 1.0351x over previous
//
#include <hip/hip_runtime.h>
#include <math.h>
#include <stdint.h>

#define B_   2
#define T_   2048
#define HID_ 2048
#define NH_  32
#define KH_  8
#define HD_  64
#define LDQKV 3072

typedef unsigned short u16;
typedef __attribute__((ext_vector_type(8))) short v8s;
typedef __attribute__((ext_vector_type(4))) float v4f;

__device__ inline v4f mfma16(v8s a, v8s b, v4f c) {
    return __builtin_amdgcn_mfma_f32_16x16x32_bf16(a, b, c, 0, 0, 0);
}
__device__ inline u16 f2bf(float f) {
    uint32_t u = __float_as_uint(f);
    u += 0x7fff + ((u >> 16) & 1);
    return (u16)(u >> 16);
}
__device__ inline float bf2f(u16 h) { return __uint_as_float(((uint32_t)h) << 16); }
__device__ inline uint32_t cvtpk_bf16(float lo, float hi) {
    uint32_t r;
    asm("v_cvt_pk_bf16_f32 %0, %1, %2" : "=v"(r) : "v"(lo), "v"(hi));
    return r;
}

// global -> LDS direct (16B per lane). LDS base must be wave-uniform.
#define GLDS(g, s)                                                                     \
    __builtin_amdgcn_global_load_lds(                                                  \
        (const __attribute__((address_space(1))) uint32_t*)(uintptr_t)(g),             \
        (__attribute__((address_space(3))) uint32_t*)(uint32_t)(uintptr_t)(s), 16, 0, 0)

// ---------------- fp32 -> bf16 elementwise ----------------
__global__ __launch_bounds__(256) void conv_f32_bf16(const float* __restrict__ in,
                                                     u16* __restrict__ out, int n4) {
    int i = blockIdx.x * 256 + threadIdx.x;
    if (i >= n4) return;
    float4 v = ((const float4*)in)[i];
    ushort4 o = {f2bf(v.x), f2bf(v.y), f2bf(v.z), f2bf(v.w)};
    ((ushort4*)out)[i] = o;
}

// ---------------- fused: 4x fp32 [R][C] -> bf16 [C][R] transpose-convert ----------------
// z=0: wq(2048x2048), z=1: wk(2048x512), z=2: wv(2048x512), z=3: wo(2048x2048)
__global__ __launch_bounds__(256) void trconv4(const float* __restrict__ s0,
                                               const float* __restrict__ s1,
                                               const float* __restrict__ s2,
                                               const float* __restrict__ s3,
                                               u16* __restrict__ d0, u16* __restrict__ d1,
                                               u16* __restrict__ d2, u16* __restrict__ d3) {
    const int z = blockIdx.z;
    const float* in = (z == 0) ? s0 : (z == 1) ? s1 : (z == 2) ? s2 : s3;
    u16* out = (z == 0) ? d0 : (z == 1) ? d1 : (z == 2) ? d2 : d3;
    const int R = 2048;
    const int C = (z == 1 || z == 2) ? 512 : 2048;
    const int r0 = blockIdx.y * 64, c0 = blockIdx.x * 64;
    if (c0 >= C) return;

    __shared__ float t[64][65];
    const int tid = threadIdx.x;
#pragma unroll
    for (int i = 0; i < 16; ++i) {
        int idx = i * 256 + tid, r = idx >> 6, c = idx & 63;
        t[r][c] = in[(size_t)(r0 + r) * C + c0 + c];
    }
    __syncthreads();
#pragma unroll
    for (int i = 0; i < 16; ++i) {
        int idx = i * 256 + tid, r = idx >> 6, c = idx & 63;
        out[(size_t)(c0 + r) * R + r0 + c] = f2bf(t[c][r]);
    }
}

// ---------------- rope sin/cos table [T][32] ----------------
__global__ __launch_bounds__(256) void rope_table(float2* __restrict__ tab) {
    int i = blockIdx.x * 256 + threadIdx.x;   // < T*32
    int t = i >> 5, p = i & 31;
    float fr = (float)t * exp2f((float)p * (-13.28771237954945f / 32.0f));
    float2 sc; sc.x = sinf(fr); sc.y = cosf(fr);
    tab[i] = sc;
}

// ---------------- V [B*T, KH*HD] (stride LDQKV) -> Vt [B][KH][HD][T] bf16 ----------------
__global__ __launch_bounds__(256) void vtrans(const u16* __restrict__ V, u16* __restrict__ Vt) {
    const int t0 = blockIdx.x * 64, kh = blockIdx.y, b = blockIdx.z;
    const int tid = threadIdx.x;
    __shared__ __align__(16) u16 tl[64][72];
#pragma unroll
    for (int p = 0; p < 2; ++p) {
        int c = p * 256 + tid, trow = c >> 3, d8 = (c & 7) * 8;
        *(v8s*)&tl[trow][d8] =
            *(const v8s*)(V + (size_t)(b * T_ + t0 + trow) * LDQKV + kh * HD_ + d8);
    }
    __syncthreads();
#pragma unroll
    for (int p = 0; p < 2; ++p) {
        int c = p * 256 + tid, drow = c >> 3, t8 = (c & 7) * 8;
        v8s o;
#pragma unroll
        for (int j = 0; j < 8; ++j) o[j] = (short)tl[t8 + j][drow];
        *(v8s*)(Vt + ((size_t)((b * KH_ + kh) * HD_) + drow) * T_ + t0 + t8) = o;
    }
}

// ---------------- bf16 GEMM: C[M,N] = A[M,K] * Bt[N,K]^T (m97 structure + XCD swizzle) ----------------
template <bool OBF>
__global__ __launch_bounds__(256) void gemm_mfma(const u16* __restrict__ A,
                                                 const u16* __restrict__ Bt,
                                                 void* __restrict__ Cv,
                                                 int M, int N, int K) {
    __shared__ __align__(16) u16 Al[128 * 32];
    __shared__ __align__(16) u16 Bl[128 * 32];
    const int tid = threadIdx.x;
    const int l = tid & 63;
    const int wid = tid >> 6;
    const int wr = wid >> 1, wc = wid & 1;
    const int lr = l & 15, lg = l >> 4;

    // bijective XCD swizzle (nwg % 8 == 0 for both launches)
    const int nx = gridDim.x;
    const int nwg = nx * gridDim.y;
    const int id = blockIdx.y * nx + blockIdx.x;
    const int sw = (id & 7) * (nwg >> 3) + (id >> 3);
    const int row0 = (sw / nx) * 128, col0 = (sw % nx) * 128;

    v4f acc[4][4];
    const v4f Z4 = {0.f, 0.f, 0.f, 0.f};
#pragma unroll
    for (int i = 0; i < 4; ++i)
#pragma unroll
        for (int j = 0; j < 4; ++j) acc[i][j] = Z4;

    const int m0 = tid & 127;
    const int ch0 = tid >> 7, ch1 = (256 + tid) >> 7;
    const u16* ga0 = A + (size_t)(row0 + m0) * K + ch0 * 8;
    const u16* ga1 = A + (size_t)(row0 + m0) * K + ch1 * 8;
    const u16* gb0 = Bt + (size_t)(col0 + m0) * K + ch0 * 8;
    const u16* gb1 = Bt + (size_t)(col0 + m0) * K + ch1 * 8;
    const int wbase = __builtin_amdgcn_readfirstlane(tid & 192);
    u16* la0 = &Al[wbase * 8];
    u16* la1 = &Al[(256 + wbase) * 8];
    u16* lb0 = &Bl[wbase * 8];
    u16* lb1 = &Bl[(256 + wbase) * 8];

    for (int k0 = 0; k0 < K; k0 += 32) {
        __syncthreads();
        GLDS(ga0 + k0, la0);
        GLDS(ga1 + k0, la1);
        GLDS(gb0 + k0, lb0);
        GLDS(gb1 + k0, lb1);
        __syncthreads();
        v8s af[4], bfr[4];
#pragma unroll
        for (int i = 0; i < 4; ++i) {
            af[i]  = *(const v8s*)&Al[(lg * 128 + wr * 64 + i * 16 + lr) * 8];
            bfr[i] = *(const v8s*)&Bl[(lg * 128 + wc * 64 + i * 16 + lr) * 8];
        }
#pragma unroll
        for (int i = 0; i < 4; ++i)
#pragma unroll
            for (int j = 0; j < 4; ++j) acc[i][j] = mfma16(af[i], bfr[j], acc[i][j]);
    }

#pragma unroll
    for (int i = 0; i < 4; ++i)
#pragma unroll
        for (int j = 0; j < 4; ++j)
#pragma unroll
            for (int r = 0; r < 4; ++r) {
                int row = row0 + wr * 64 + i * 16 + lg * 4 + r;
                int col = col0 + wc * 64 + j * 16 + lr;
                float v = acc[i][j][r];
                if (OBF) ((u16*)Cv)[(size_t)row * N + col] = f2bf(v);
                else     ((float*)Cv)[(size_t)row * N + col] = v;
            }
}

// ---------------- fused RoPE + RMSNorm (q then k sections), bf16 in-place ----------------
__global__ __launch_bounds__(256) void rope_rms2(u16* __restrict__ X,
                                                 const float* __restrict__ qw,
                                                 const float* __restrict__ kw,
                                                 const float2* __restrict__ tab) {
    int pair = blockIdx.x * 4 + (threadIdx.x >> 6);
    const int lane = threadIdx.x & 63;
    int row, h, off;
    const float* w;
    if (pair < 4096 * 32) { row = pair >> 5; h = pair & 31; off = 0; w = qw; }
    else { pair -= 4096 * 32; row = pair >> 3; h = pair & 7; off = 2048; w = kw; }
    const int t = row & (T_ - 1);

    u16* px = X + (size_t)row * LDQKV + off + h * HD_ + lane;
    float x = bf2f(*px);
    float2 sc = tab[t * 32 + (lane >> 1)];
    float other = __shfl_xor(x, 1, 64);
    float r = (lane & 1) ? fmaf(other, sc.x, x * sc.y) : fmaf(x, sc.y, -(other * sc.x));
    float sq = r * r;
#pragma unroll
    for (int offv = 32; offv >= 1; offv >>= 1) sq += __shfl_xor(sq, offv, 64);
    float invn = rsqrtf(sq * (1.0f / 64.0f) + 1e-6f);
    *px = f2bf(r * invn * w[lane]);
}

// ---------------- MFMA flash attention v3: 8 waves, QBLK=128, KVBLK=128 ----------------
// grid (T/128, KH, B) = 256 blocks (1/CU, all co-resident). Wave w owns q-rows
// [qt*128 + w*16, +16) for all 4 grouped heads. Swapped-operand MFMA + fixed-max softmax.
__global__ __launch_bounds__(512, 2) void attn_mfma(const u16* __restrict__ Qb,
                                                    const u16* __restrict__ Kb,
                                                    const u16* __restrict__ VTb,
                                                    u16* __restrict__ Ctx) {
    const int qt = gridDim.x - 1 - blockIdx.x;   // 0..15, big tiles first
    const int kh = blockIdx.y, b = blockIdx.z;
    const int tid = threadIdx.x, w = tid >> 6, l = tid & 63;
    const int lr = l & 15, lg = l >> 4;

    __shared__ __align__(16) u16 Kbuf[2][128 * 64];     // [k-row][d] swizzled, 16KB each
    __shared__ __align__(16) u16 Vbuf[2][64 * 128];     // [d][k-col] swizzled, 16KB each
    __shared__ __align__(16) uint32_t Ps[8][16][68];    // [wave][q][packed col pair]

    // Q fragments for the 4 grouped heads
    v8s qf[4][2];
#pragma unroll
    for (int g = 0; g < 4; ++g) {
        const u16* qp = Qb + (size_t)(b * T_ + qt * 128 + w * 16 + lr) * LDQKV +
                        (kh * 4 + g) * HD_ + lg * 8;
        qf[g][0] = *(const v8s*)qp;
        qf[g][1] = *(const v8s*)(qp + 32);
    }

    // staging: 1024 16B-units per tile each for K and Vt; unit u = i*512 + tid
    const int u0 = tid, u1 = 512 + tid;
    const int kr0 = u0 >> 3, kc0 = (u0 & 7) ^ (kr0 & 7);
    const int kr1 = u1 >> 3, kc1 = (u1 & 7) ^ (kr1 & 7);
    const u16* kg0 = Kb + (size_t)(b * T_ + kr0) * LDQKV + kh * HD_ + kc0 * 8;
    const u16* kg1 = Kb + (size_t)(b * T_ + kr1) * LDQKV + kh * HD_ + kc1 * 8;
    const int vr0 = u0 >> 4, vc0 = (u0 & 15) ^ (vr0 & 15);
    const int vr1 = u1 >> 4, vc1 = (u1 & 15) ^ (vr1 & 15);
    const u16* vg0 = VTb + ((size_t)((b * KH_ + kh) * HD_) + vr0) * T_ + vc0 * 8;
    const u16* vg1 = VTb + ((size_t)((b * KH_ + kh) * HD_) + vr1) * T_ + vc1 * 8;
    const int wu64 = __builtin_amdgcn_readfirstlane(w * 64);

    const v4f Z4 = {0.f, 0.f, 0.f, 0.f};
    v4f o[4][4];
    float lsum[4];
#pragma unroll
    for (int g = 0; g < 4; ++g) {
        lsum[g] = 0.f;
#pragma unroll
        for (int d = 0; d < 4; ++d) o[g][d] = Z4;
    }

    auto stage = [&](int bufi, int kt) {
        const size_t ko = (size_t)kt * 128 * LDQKV;
        const int vo = kt * 128;
        GLDS(kg0 + ko, &Kbuf[bufi][wu64 * 8]);
        GLDS(kg1 + ko, &Kbuf[bufi][(512 + wu64) * 8]);
        GLDS(vg0 + vo, &Vbuf[bufi][wu64 * 8]);
        GLDS(vg1 + vo, &Vbuf[bufi][(512 + wu64) * 8]);
    };

    const float C1 = 0.18033688011112042f;    // 0.125 * log2(e)
    const float C0 = -11.541560327111707f;    // -8 * log2(e)
    const int swz8 = lr & 7;

    auto body = [&](const u16* Kc, const u16* Vc, bool masked) {
#pragma unroll
        for (int g = 0; g < 4; ++g) {
            // S^T = K Q^T : lane holds q-row lr, cols j*16 + lg*4 + r (128 cols)
            v4f s[8];
#pragma unroll
            for (int j = 0; j < 8; ++j) s[j] = Z4;
#pragma unroll
            for (int ks = 0; ks < 2; ++ks) {
#pragma unroll
                for (int j = 0; j < 8; ++j)
                    s[j] = mfma16(*(const v8s*)&Kc[(j * 16 + lr) * 64 + (((ks * 4 + lg) ^ swz8) * 8)],
                                  qf[g][ks], s[j]);
            }
#pragma unroll
            for (int j = 0; j < 8; ++j) {
                float p[4];
#pragma unroll
                for (int r = 0; r < 4; ++r) {
                    float pv = exp2f(fmaf(s[j][r], C1, C0));
                    if (masked && (j * 16 + lg * 4 + r) > (w * 16 + lr)) pv = 0.f;
                    p[r] = pv;
                }
                lsum[g] += (p[0] + p[1]) + (p[2] + p[3]);
                Ps[w][lr][j * 8 + lg * 2 + 0] = cvtpk_bf16(p[0], p[1]);
                Ps[w][lr][j * 8 + lg * 2 + 1] = cvtpk_bf16(p[2], p[3]);
            }
            asm volatile("s_waitcnt lgkmcnt(0)" ::: "memory");
            // O^T += V^T P^T : lane holds q = lr, d-rows dj*16 + lg*4 + r
#pragma unroll
            for (int ks = 0; ks < 4; ++ks) {
                v8s pf = *(const v8s*)&Ps[w][lr][ks * 16 + lg * 4];
#pragma unroll
                for (int dj = 0; dj < 4; ++dj)
                    o[g][dj] = mfma16(*(const v8s*)&Vc[(dj * 16 + lr) * 128 + (((ks * 4 + lg) ^ lr) * 8)],
                                      pf, o[g][dj]);
            }
        }
    };

    stage(0, 0);
    int buf = 0;
    for (int kt = 0; kt < qt; ++kt) {
        stage(buf ^ 1, kt + 1);
        asm volatile("s_waitcnt vmcnt(4)" ::: "memory");
        __builtin_amdgcn_s_barrier();
        body(Kbuf[buf], Vbuf[buf], false);
        asm volatile("s_waitcnt lgkmcnt(0)" ::: "memory");
        __builtin_amdgcn_s_barrier();
        buf ^= 1;
    }
    asm volatile("s_waitcnt vmcnt(0)" ::: "memory");
    __builtin_amdgcn_s_barrier();
    body(Kbuf[buf], Vbuf[buf], true);

    // reduce lane-local partial sums across the 4 lg replicas of each q-row
#pragma unroll
    for (int g = 0; g < 4; ++g) {
        float t1 = lsum[g] + __shfl_xor(lsum[g], 16, 64);
        float inv = 1.0f / (t1 + __shfl_xor(t1, 32, 64));
        u16* cp = Ctx + (size_t)(b * T_ + qt * 128 + w * 16 + lr) * (NH_ * HD_) +
                  (kh * 4 + g) * HD_ + lg * 4;
#pragma unroll
        for (int dj = 0; dj < 4; ++dj) {
            ushort4 ov = {f2bf(o[g][dj][0] * inv), f2bf(o[g][dj][1] * inv),
                          f2bf(o[g][dj][2] * inv), f2bf(o[g][dj][3] * inv)};
            *(ushort4*)(cp + dj * 16) = ov;
        }
    }
}

// ---------------- launch ----------------
extern "C" void kernel_launch(void* const* d_in, const int* in_sizes, int n_in,
                              void* d_out, int out_size, void* d_ws, size_t ws_size,
                              hipStream_t stream) {
    const float* hs  = (const float*)d_in[0];
    const float* wq  = (const float*)d_in[1];
    const float* wk  = (const float*)d_in[2];
    const float* wv  = (const float*)d_in[3];
    const float* wo  = (const float*)d_in[4];
    const float* qnw = (const float*)d_in[5];
    const float* knw = (const float*)d_in[6];
    float* out = (float*)d_out;
    (void)in_sizes; (void)n_in; (void)out_size; (void)ws_size;

    char* p = (char*)d_ws;
    auto alloc = [&](size_t bytes) { void* r = (void*)p; p += (bytes + 255) & ~(size_t)255; return r; };
    u16* hsb   = (u16*)alloc((size_t)4096 * 2048 * 2);
    u16* wqkvt = (u16*)alloc((size_t)3072 * 2048 * 2);   // [wq^T ; wk^T ; wv^T]
    u16* qkvb  = (u16*)alloc((size_t)4096 * 3072 * 2);   // [q | k | v]
    u16* wot   = (u16*)alloc((size_t)2048 * 2048 * 2);
    u16* ctx   = (u16*)alloc((size_t)4096 * 2048 * 2);
    u16* vt    = (u16*)alloc((size_t)B_ * KH_ * HD_ * T_ * 2);
    float2* tab = (float2*)alloc((size_t)T_ * 32 * sizeof(float2));

    conv_f32_bf16<<<(4096 * 2048 / 4 + 255) / 256, 256, 0, stream>>>(hs, hsb, 4096 * 2048 / 4);
    trconv4<<<dim3(32, 32, 4), 256, 0, stream>>>(wq, wk, wv, wo,
                                                 wqkvt,
                                                 wqkvt + (size_t)2048 * 2048,
                                                 wqkvt + (size_t)2560 * 2048,
                                                 wot);
    rope_table<<<(T_ * 32) / 256, 256, 0, stream>>>(tab);

    gemm_mfma<true><<<dim3(3072 / 128, 4096 / 128), 256, 0, stream>>>(hsb, wqkvt, qkvb, 4096, 3072, 2048);

    rope_rms2<<<(4096 * 40) / 4, 256, 0, stream>>>(qkvb, qnw, knw, tab);
    vtrans<<<dim3(T_ / 64, KH_, B_), 256, 0, stream>>>(qkvb + 2560, vt);

    attn_mfma<<<dim3(T_ / 128, KH_, B_), 512, 0, stream>>>(qkvb, qkvb + 2048, vt, ctx);

    gemm_mfma<false><<<dim3(2048 / 128, 4096 / 128), 256, 0, stream>>>(ctx, wot, out, 4096, 2048, 2048);
}

// Round 8
// 358.263 us; speedup vs baseline: 10.0521x; 1.2300x over previous
//
#include <hip/hip_runtime.h>
#include <math.h>
#include <stdint.h>

#define B_   2
#define T_   2048
#define HID_ 2048
#define NH_  32
#define KH_  8
#define HD_  64
#define LDQKV 3072

typedef unsigned short u16;
typedef __attribute__((ext_vector_type(8))) short v8s;
typedef __attribute__((ext_vector_type(4))) float v4f;

__device__ inline v4f mfma16(v8s a, v8s b, v4f c) {
    return __builtin_amdgcn_mfma_f32_16x16x32_bf16(a, b, c, 0, 0, 0);
}
__device__ inline u16 f2bf(float f) {
    uint32_t u = __float_as_uint(f);
    u += 0x7fff + ((u >> 16) & 1);
    return (u16)(u >> 16);
}
__device__ inline float bf2f(u16 h) { return __uint_as_float(((uint32_t)h) << 16); }
__device__ inline uint32_t cvtpk_bf16(float lo, float hi) {
    uint32_t r;
    asm("v_cvt_pk_bf16_f32 %0, %1, %2" : "=v"(r) : "v"(lo), "v"(hi));
    return r;
}

// global -> LDS direct (16B per lane). LDS base must be wave-uniform.
#define GLDS(g, s)                                                                     \
    __builtin_amdgcn_global_load_lds(                                                  \
        (const __attribute__((address_space(1))) uint32_t*)(uintptr_t)(g),             \
        (__attribute__((address_space(3))) uint32_t*)(uint32_t)(uintptr_t)(s), 16, 0, 0)

#define BAR() __builtin_amdgcn_s_barrier()
#define LG0() asm volatile("s_waitcnt lgkmcnt(0)" ::: "memory")
#define VMW(n) asm volatile("s_waitcnt vmcnt(" #n ")" ::: "memory")

// ---------------- fp32 -> bf16 elementwise ----------------
__global__ __launch_bounds__(256) void conv_f32_bf16(const float* __restrict__ in,
                                                     u16* __restrict__ out, int n4) {
    int i = blockIdx.x * 256 + threadIdx.x;
    if (i >= n4) return;
    float4 v = ((const float4*)in)[i];
    ushort4 o = {f2bf(v.x), f2bf(v.y), f2bf(v.z), f2bf(v.w)};
    ((ushort4*)out)[i] = o;
}

// ---------------- fused: 4x fp32 [R][C] -> bf16 [C][R] transpose-convert ----------------
__global__ __launch_bounds__(256) void trconv4(const float* __restrict__ s0,
                                               const float* __restrict__ s1,
                                               const float* __restrict__ s2,
                                               const float* __restrict__ s3,
                                               u16* __restrict__ d0, u16* __restrict__ d1,
                                               u16* __restrict__ d2, u16* __restrict__ d3) {
    const int z = blockIdx.z;
    const float* in = (z == 0) ? s0 : (z == 1) ? s1 : (z == 2) ? s2 : s3;
    u16* out = (z == 0) ? d0 : (z == 1) ? d1 : (z == 2) ? d2 : d3;
    const int R = 2048;
    const int C = (z == 1 || z == 2) ? 512 : 2048;
    const int r0 = blockIdx.y * 64, c0 = blockIdx.x * 64;
    if (c0 >= C) return;

    __shared__ float t[64][65];
    const int tid = threadIdx.x;
#pragma unroll
    for (int i = 0; i < 16; ++i) {
        int idx = i * 256 + tid, r = idx >> 6, c = idx & 63;
        t[r][c] = in[(size_t)(r0 + r) * C + c0 + c];
    }
    __syncthreads();
#pragma unroll
    for (int i = 0; i < 16; ++i) {
        int idx = i * 256 + tid, r = idx >> 6, c = idx & 63;
        out[(size_t)(c0 + r) * R + r0 + c] = f2bf(t[c][r]);
    }
}

// ---------------- rope sin/cos table [T][32] ----------------
__global__ __launch_bounds__(256) void rope_table(float2* __restrict__ tab) {
    int i = blockIdx.x * 256 + threadIdx.x;   // < T*32
    int t = i >> 5, p = i & 31;
    float fr = (float)t * exp2f((float)p * (-13.28771237954945f / 32.0f));
    float2 sc; sc.x = sinf(fr); sc.y = cosf(fr);
    tab[i] = sc;
}

// ---------------- V [B*T, KH*HD] (stride LDQKV) -> Vt [B][KH][HD][T] bf16 ----------------
__global__ __launch_bounds__(256) void vtrans(const u16* __restrict__ V, u16* __restrict__ Vt) {
    const int t0 = blockIdx.x * 64, kh = blockIdx.y, b = blockIdx.z;
    const int tid = threadIdx.x;
    __shared__ __align__(16) u16 tl[64][72];
#pragma unroll
    for (int p = 0; p < 2; ++p) {
        int c = p * 256 + tid, trow = c >> 3, d8 = (c & 7) * 8;
        *(v8s*)&tl[trow][d8] =
            *(const v8s*)(V + (size_t)(b * T_ + t0 + trow) * LDQKV + kh * HD_ + d8);
    }
    __syncthreads();
#pragma unroll
    for (int p = 0; p < 2; ++p) {
        int c = p * 256 + tid, drow = c >> 3, t8 = (c & 7) * 8;
        v8s o;
#pragma unroll
        for (int j = 0; j < 8; ++j) o[j] = (short)tl[t8 + j][drow];
        *(v8s*)(Vt + ((size_t)((b * KH_ + kh) * HD_) + drow) * T_ + t0 + t8) = o;
    }
}

// ======== 8-phase 256-row GEMM: C[M,N] = A[M,K] * Bt[N,K]^T ========
// 8 waves, BK=64, K-half staging units (16KB, 2 GLDS/thread), double-buffered LDS,
// counted vmcnt (never 0 mid-loop), granule-permutation swizzle p = row*4 + (c16 ^ ((row>>1)&3))
// -> conflict-free ds_read_b128 frags with linear global_load_lds dests.
template <int BN, bool OBF>
__global__ __launch_bounds__(512, 2) void gemm8(const u16* __restrict__ A,
                                                const u16* __restrict__ Bt,
                                                void* __restrict__ Cv,
                                                int M, int N, int K) {
    constexpr int NW_N = BN / 64;              // 4 | 2
    constexpr int MF = (NW_N == 4) ? 8 : 4;    // m-frags per wave
    constexpr int MH = MF / 2;

    __shared__ __align__(16) u16 Al[2][2][8192];
    __shared__ __align__(16) u16 Bl[2][2][BN * 32];

    const int tid = threadIdx.x;
    const int w = tid >> 6, l = tid & 63;
    const int lr = l & 15, lg = l >> 4;
    const int warp_m = w / NW_N, warp_n = w % NW_N;

    // bijective XCD swizzle (nwg % 8 == 0 for all launches here)
    const int nx = gridDim.x;
    const int nwg = nx * gridDim.y;
    const int id = blockIdx.y * nx + blockIdx.x;
    const int sw = (id & 7) * (nwg >> 3) + (id >> 3);
    const int row0 = (sw / nx) * 256, col0 = (sw % nx) * BN;

    const int NT = K >> 6;

    // staging: thread t covers LDS granule t (and t+512 for q=1) of each unit
    const int srow = tid >> 2;
    const int sg = (tid & 3) ^ ((tid >> 3) & 3);
    const u16* aS = A + (size_t)(row0 + srow) * K + sg * 8;
    const u16* bS = Bt + (size_t)(col0 + srow) * K + sg * 8;
    const int wbase = __builtin_amdgcn_readfirstlane(w) * 512;

    // frag read offsets (elems): p = row*4 + (lg ^ ((row>>1)&3)); row-base swz reduces to lr
    const int aoff = ((warp_m * (MF * 16) + lr) * 4 + (lg ^ ((lr >> 1) & 3))) * 8;
    const int boff = ((warp_n * 64 + lr) * 4 + (lg ^ ((lr >> 1) & 3))) * 8;

#define SA(b_, kh_, tau_)                                                              \
    {                                                                                  \
        GLDS(aS + (tau_) * 64 + (kh_) * 32, &Al[b_][kh_][wbase]);                      \
        GLDS(aS + (size_t)128 * K + (tau_) * 64 + (kh_) * 32, &Al[b_][kh_][4096 + wbase]); \
    }
#define SB(b_, kh_, tau_)                                                              \
    {                                                                                  \
        GLDS(bS + (tau_) * 64 + (kh_) * 32, &Bl[b_][kh_][wbase]);                      \
        if constexpr (BN == 256)                                                       \
            GLDS(bS + (size_t)128 * K + (tau_) * 64 + (kh_) * 32, &Bl[b_][kh_][4096 + wbase]); \
    }
#define LDB(U)                                                                         \
    _Pragma("unroll") for (int j = 0; j < 4; ++j)                                      \
        bf[j] = *(const v8s*)((U) + boff + j * 512);
#define LDA(U, mh)                                                                     \
    _Pragma("unroll") for (int fi = 0; fi < MH; ++fi)                                  \
        af[fi] = *(const v8s*)((U) + aoff + ((mh) * MH + fi) * 512);
#define MM(mh)                                                                         \
    _Pragma("unroll") for (int fi = 0; fi < MH; ++fi)                                  \
        _Pragma("unroll") for (int j = 0; j < 4; ++j)                                  \
            acc[(mh) * MH + fi][j] = mfma16(af[fi], bf[j], acc[(mh) * MH + fi][j]);

    v4f acc[MF][4];
    const v4f Z4 = {0.f, 0.f, 0.f, 0.f};
#pragma unroll
    for (int i = 0; i < MF; ++i)
#pragma unroll
        for (int j = 0; j < 4; ++j) acc[i][j] = Z4;

    // prologue: U0(0) U1(0) U2(0) U3(0) U0(1) U1(1); wait all but last 4 units
    SA(0, 0, 0); SB(0, 0, 0); SA(0, 1, 0); SB(0, 1, 0); SA(1, 0, 1); SB(1, 0, 1);
    if constexpr (BN == 256) { VMW(8); } else { VMW(6); }
    BAR();

    int buf = 0;
    for (int tau = 0; tau < NT; ++tau) {
        const u16* A0 = &Al[buf][0][0];
        const u16* A1 = &Al[buf][1][0];
        const u16* B0 = &Bl[buf][0][0];
        const u16* B1 = &Bl[buf][1][0];
        const int nb = buf ^ 1;
        const bool s1 = (tau + 1 < NT), s2 = (tau + 2 < NT);
        v8s af[MH], bf[4];

        // ---- phase 1 (kh0, mh0): stage U2(tau+1)=A.kh1 -> nb ----
        LDB(B0); LDA(A0, 0);
        if (s1) SA(nb, 1, tau + 1);
        BAR();
        __builtin_amdgcn_s_setprio(1); MM(0); __builtin_amdgcn_s_setprio(0);
        BAR();
        // ---- phase 2 (kh0, mh1): stage U3(tau+1)=B.kh1 -> nb ----
        LDA(A0, 1);
        if (s1) SB(nb, 1, tau + 1);
        BAR();
        __builtin_amdgcn_s_setprio(1); MM(1); __builtin_amdgcn_s_setprio(0);
        LG0();
        if (s1) { if constexpr (BN == 256) { VMW(8); } else { VMW(6); } }
        else    { VMW(0); }
        BAR();
        // ---- phase 3 (kh1, mh0): stage U0(tau+2)=A.kh0 -> buf ----
        LDB(B1); LDA(A1, 0);
        if (s2) SA(buf, 0, tau + 2);
        BAR();
        __builtin_amdgcn_s_setprio(1); MM(0); __builtin_amdgcn_s_setprio(0);
        BAR();
        // ---- phase 4 (kh1, mh1): stage U1(tau+2)=B.kh0 -> buf ----
        LDA(A1, 1);
        if (s2) SB(buf, 0, tau + 2);
        BAR();
        __builtin_amdgcn_s_setprio(1); MM(1); __builtin_amdgcn_s_setprio(0);
        LG0();
        if (s2)      { if constexpr (BN == 256) { VMW(8); } else { VMW(6); } }
        else if (s1) { if constexpr (BN == 256) { VMW(4); } else { VMW(3); } }
        BAR();
        buf ^= 1;
    }

    // epilogue
#pragma unroll
    for (int fi = 0; fi < MF; ++fi)
#pragma unroll
        for (int j = 0; j < 4; ++j)
#pragma unroll
            for (int r = 0; r < 4; ++r) {
                int row = row0 + warp_m * (MF * 16) + fi * 16 + lg * 4 + r;
                int col = col0 + warp_n * 64 + j * 16 + lr;
                float v = acc[fi][j][r];
                if (OBF) ((u16*)Cv)[(size_t)row * N + col] = f2bf(v);
                else     ((float*)Cv)[(size_t)row * N + col] = v;
            }
#undef SA
#undef SB
#undef LDA
#undef LDB
#undef MM
}

// ---------------- fused RoPE + RMSNorm (q then k sections), bf16 in-place ----------------
__global__ __launch_bounds__(256) void rope_rms2(u16* __restrict__ X,
                                                 const float* __restrict__ qw,
                                                 const float* __restrict__ kw,
                                                 const float2* __restrict__ tab) {
    int pair = blockIdx.x * 4 + (threadIdx.x >> 6);
    const int lane = threadIdx.x & 63;
    int row, h, off;
    const float* w;
    if (pair < 4096 * 32) { row = pair >> 5; h = pair & 31; off = 0; w = qw; }
    else { pair -= 4096 * 32; row = pair >> 3; h = pair & 7; off = 2048; w = kw; }
    const int t = row & (T_ - 1);

    u16* px = X + (size_t)row * LDQKV + off + h * HD_ + lane;
    float x = bf2f(*px);
    float2 sc = tab[t * 32 + (lane >> 1)];
    float other = __shfl_xor(x, 1, 64);
    float r = (lane & 1) ? fmaf(other, sc.x, x * sc.y) : fmaf(x, sc.y, -(other * sc.x));
    float sq = r * r;
#pragma unroll
    for (int offv = 32; offv >= 1; offv >>= 1) sq += __shfl_xor(sq, offv, 64);
    float invn = rsqrtf(sq * (1.0f / 64.0f) + 1e-6f);
    *px = f2bf(r * invn * w[lane]);
}

// ---------------- MFMA flash attention v3: 8 waves, QBLK=128, KVBLK=128 ----------------
__global__ __launch_bounds__(512, 2) void attn_mfma(const u16* __restrict__ Qb,
                                                    const u16* __restrict__ Kb,
                                                    const u16* __restrict__ VTb,
                                                    u16* __restrict__ Ctx) {
    const int qt = gridDim.x - 1 - blockIdx.x;   // 0..15, big tiles first
    const int kh = blockIdx.y, b = blockIdx.z;
    const int tid = threadIdx.x, w = tid >> 6, l = tid & 63;
    const int lr = l & 15, lg = l >> 4;

    __shared__ __align__(16) u16 Kbuf[2][128 * 64];
    __shared__ __align__(16) u16 Vbuf[2][64 * 128];
    __shared__ __align__(16) uint32_t Ps[8][16][68];

    v8s qf[4][2];
#pragma unroll
    for (int g = 0; g < 4; ++g) {
        const u16* qp = Qb + (size_t)(b * T_ + qt * 128 + w * 16 + lr) * LDQKV +
                        (kh * 4 + g) * HD_ + lg * 8;
        qf[g][0] = *(const v8s*)qp;
        qf[g][1] = *(const v8s*)(qp + 32);
    }

    const int u0 = tid, u1 = 512 + tid;
    const int kr0 = u0 >> 3, kc0 = (u0 & 7) ^ (kr0 & 7);
    const int kr1 = u1 >> 3, kc1 = (u1 & 7) ^ (kr1 & 7);
    const u16* kg0 = Kb + (size_t)(b * T_ + kr0) * LDQKV + kh * HD_ + kc0 * 8;
    const u16* kg1 = Kb + (size_t)(b * T_ + kr1) * LDQKV + kh * HD_ + kc1 * 8;
    const int vr0 = u0 >> 4, vc0 = (u0 & 15) ^ (vr0 & 15);
    const int vr1 = u1 >> 4, vc1 = (u1 & 15) ^ (vr1 & 15);
    const u16* vg0 = VTb + ((size_t)((b * KH_ + kh) * HD_) + vr0) * T_ + vc0 * 8;
    const u16* vg1 = VTb + ((size_t)((b * KH_ + kh) * HD_) + vr1) * T_ + vc1 * 8;
    const int wu64 = __builtin_amdgcn_readfirstlane(w * 64);

    const v4f Z4 = {0.f, 0.f, 0.f, 0.f};
    v4f o[4][4];
    float lsum[4];
#pragma unroll
    for (int g = 0; g < 4; ++g) {
        lsum[g] = 0.f;
#pragma unroll
        for (int d = 0; d < 4; ++d) o[g][d] = Z4;
    }

    auto stage = [&](int bufi, int kt) {
        const size_t ko = (size_t)kt * 128 * LDQKV;
        const int vo = kt * 128;
        GLDS(kg0 + ko, &Kbuf[bufi][wu64 * 8]);
        GLDS(kg1 + ko, &Kbuf[bufi][(512 + wu64) * 8]);
        GLDS(vg0 + vo, &Vbuf[bufi][wu64 * 8]);
        GLDS(vg1 + vo, &Vbuf[bufi][(512 + wu64) * 8]);
    };

    const float C1 = 0.18033688011112042f;    // 0.125 * log2(e)
    const float C0 = -11.541560327111707f;    // -8 * log2(e)
    const int swz8 = lr & 7;

    auto body = [&](const u16* Kc, const u16* Vc, bool masked) {
#pragma unroll
        for (int g = 0; g < 4; ++g) {
            v4f s[8];
#pragma unroll
            for (int j = 0; j < 8; ++j) s[j] = Z4;
#pragma unroll
            for (int ks = 0; ks < 2; ++ks) {
#pragma unroll
                for (int j = 0; j < 8; ++j)
                    s[j] = mfma16(*(const v8s*)&Kc[(j * 16 + lr) * 64 + (((ks * 4 + lg) ^ swz8) * 8)],
                                  qf[g][ks], s[j]);
            }
#pragma unroll
            for (int j = 0; j < 8; ++j) {
                float p[4];
#pragma unroll
                for (int r = 0; r < 4; ++r) {
                    float pv = exp2f(fmaf(s[j][r], C1, C0));
                    if (masked && (j * 16 + lg * 4 + r) > (w * 16 + lr)) pv = 0.f;
                    p[r] = pv;
                }
                lsum[g] += (p[0] + p[1]) + (p[2] + p[3]);
                Ps[w][lr][j * 8 + lg * 2 + 0] = cvtpk_bf16(p[0], p[1]);
                Ps[w][lr][j * 8 + lg * 2 + 1] = cvtpk_bf16(p[2], p[3]);
            }
            asm volatile("s_waitcnt lgkmcnt(0)" ::: "memory");
#pragma unroll
            for (int ks = 0; ks < 4; ++ks) {
                v8s pf = *(const v8s*)&Ps[w][lr][ks * 16 + lg * 4];
#pragma unroll
                for (int dj = 0; dj < 4; ++dj)
                    o[g][dj] = mfma16(*(const v8s*)&Vc[(dj * 16 + lr) * 128 + (((ks * 4 + lg) ^ lr) * 8)],
                                      pf, o[g][dj]);
            }
        }
    };

    stage(0, 0);
    int buf = 0;
    for (int kt = 0; kt < qt; ++kt) {
        stage(buf ^ 1, kt + 1);
        asm volatile("s_waitcnt vmcnt(4)" ::: "memory");
        __builtin_amdgcn_s_barrier();
        body(Kbuf[buf], Vbuf[buf], false);
        asm volatile("s_waitcnt lgkmcnt(0)" ::: "memory");
        __builtin_amdgcn_s_barrier();
        buf ^= 1;
    }
    asm volatile("s_waitcnt vmcnt(0)" ::: "memory");
    __builtin_amdgcn_s_barrier();
    body(Kbuf[buf], Vbuf[buf], true);

#pragma unroll
    for (int g = 0; g < 4; ++g) {
        float t1 = lsum[g] + __shfl_xor(lsum[g], 16, 64);
        float inv = 1.0f / (t1 + __shfl_xor(t1, 32, 64));
        u16* cp = Ctx + (size_t)(b * T_ + qt * 128 + w * 16 + lr) * (NH_ * HD_) +
                  (kh * 4 + g) * HD_ + lg * 4;
#pragma unroll
        for (int dj = 0; dj < 4; ++dj) {
            ushort4 ov = {f2bf(o[g][dj][0] * inv), f2bf(o[g][dj][1] * inv),
                          f2bf(o[g][dj][2] * inv), f2bf(o[g][dj][3] * inv)};
            *(ushort4*)(cp + dj * 16) = ov;
        }
    }
}

// ---------------- launch ----------------
extern "C" void kernel_launch(void* const* d_in, const int* in_sizes, int n_in,
                              void* d_out, int out_size, void* d_ws, size_t ws_size,
                              hipStream_t stream) {
    const float* hs  = (const float*)d_in[0];
    const float* wq  = (const float*)d_in[1];
    const float* wk  = (const float*)d_in[2];
    const float* wv  = (const float*)d_in[3];
    const float* wo  = (const float*)d_in[4];
    const float* qnw = (const float*)d_in[5];
    const float* knw = (const float*)d_in[6];
    float* out = (float*)d_out;
    (void)in_sizes; (void)n_in; (void)out_size; (void)ws_size;

    char* p = (char*)d_ws;
    auto alloc = [&](size_t bytes) { void* r = (void*)p; p += (bytes + 255) & ~(size_t)255; return r; };
    u16* hsb   = (u16*)alloc((size_t)4096 * 2048 * 2);
    u16* wqkvt = (u16*)alloc((size_t)3072 * 2048 * 2);   // [wq^T ; wk^T ; wv^T]
    u16* qkvb  = (u16*)alloc((size_t)4096 * 3072 * 2);   // [q | k | v]
    u16* wot   = (u16*)alloc((size_t)2048 * 2048 * 2);
    u16* ctx   = (u16*)alloc((size_t)4096 * 2048 * 2);
    u16* vt    = (u16*)alloc((size_t)B_ * KH_ * HD_ * T_ * 2);
    float2* tab = (float2*)alloc((size_t)T_ * 32 * sizeof(float2));

    conv_f32_bf16<<<(4096 * 2048 / 4 + 255) / 256, 256, 0, stream>>>(hs, hsb, 4096 * 2048 / 4);
    trconv4<<<dim3(32, 32, 4), 256, 0, stream>>>(wq, wk, wv, wo,
                                                 wqkvt,
                                                 wqkvt + (size_t)2048 * 2048,
                                                 wqkvt + (size_t)2560 * 2048,
                                                 wot);
    rope_table<<<(T_ * 32) / 256, 256, 0, stream>>>(tab);

    gemm8<256, true><<<dim3(3072 / 256, 4096 / 256), 512, 0, stream>>>(hsb, wqkvt, qkvb, 4096, 3072, 2048);

    rope_rms2<<<(4096 * 40) / 4, 256, 0, stream>>>(qkvb, qnw, knw, tab);
    vtrans<<<dim3(T_ / 64, KH_, B_), 256, 0, stream>>>(qkvb + 2560, vt);

    attn_mfma<<<dim3(T_ / 128, KH_, B_), 512, 0, stream>>>(qkvb, qkvb + 2048, vt, ctx);

    gemm8<128, false><<<dim3(2048 / 128, 4096 / 256), 512, 0, stream>>>(ctx, wot, out, 4096, 2048, 2048);
}